// Round 1
// baseline (1859.551 us; speedup 1.0000x reference)
//
#include <hip/hip_runtime.h>
#include <math.h>

#define BATCH 32
#define HH 1024
#define WW 1024
#define WR 513
#define NPIX (HH * WR)
#define TWO_PI_F 6.28318530717958647692f

__device__ __forceinline__ int bitrev10(unsigned i) { return (int)(__brev(i) >> 22); }

// ---------------------------------------------------------------------------
// Kernel A: per-row 1024-pt FFT of real input; store k = 0..512 (rfft)
// ---------------------------------------------------------------------------
__global__ __launch_bounds__(256) void row_fft_kernel(const float* __restrict__ x,
                                                      float2* __restrict__ rf) {
    __shared__ float re[1024], im[1024], twr[512], twi[512];
    const int t = threadIdx.x;
    const long long row = blockIdx.x;
    const float* xr = x + row * (long long)WW;

    for (int j = t; j < 512; j += 256) {
        float s, c;
        __sincosf(-TWO_PI_F * (float)j * (1.0f / 1024.0f), &s, &c);
        twr[j] = c; twi[j] = s;
    }
    for (int i = t; i < 1024; i += 256) {
        int j = bitrev10((unsigned)i);
        re[j] = xr[i];
        im[j] = 0.0f;
    }
    __syncthreads();
#pragma unroll
    for (int s = 1; s <= 10; ++s) {
        const int half = 1 << (s - 1);
        const int m = half << 1;
#pragma unroll
        for (int r = 0; r < 2; ++r) {
            int bf = t + r * 256;               // 512 butterflies per stage
            int grp = bf >> (s - 1);
            int pos = bf & (half - 1);
            int i1 = grp * m + pos;
            int i2 = i1 + half;
            int ti = pos << (10 - s);
            float wr = twr[ti], wi = twi[ti];
            float xr2 = re[i2], xi2 = im[i2];
            float tr = wr * xr2 - wi * xi2;
            float tc = wr * xi2 + wi * xr2;
            float ur = re[i1], ui = im[i1];
            re[i1] = ur + tr; im[i1] = ui + tc;
            re[i2] = ur - tr; im[i2] = ui - tc;
        }
        __syncthreads();
    }
    float2* out = rf + row * (long long)WR;
    for (int k = t; k < WR; k += 256) out[k] = make_float2(re[k], im[k]);
}

// ---------------------------------------------------------------------------
// Kernel B: per-(batch,w) 1024-pt column FFT; epilogue: magnitude max per
// batch (atomicMax on float bits), unwrapped phase written in place into .x
// ---------------------------------------------------------------------------
__global__ __launch_bounds__(256) void col_fft_kernel(float2* __restrict__ rf,
                                                      float* __restrict__ magmax) {
    __shared__ float re[1024], im[1024], twr[512], twi[512];
    const int t = threadIdx.x;
    const int c = blockIdx.x;
    const int b = c / WR;
    const int w = c - b * WR;
    float2* base = rf + (long long)b * HH * WR + w;

    for (int j = t; j < 512; j += 256) {
        float s, cc;
        __sincosf(-TWO_PI_F * (float)j * (1.0f / 1024.0f), &s, &cc);
        twr[j] = cc; twi[j] = s;
    }
    for (int i = t; i < 1024; i += 256) {
        float2 v = base[(long long)i * WR];
        int j = bitrev10((unsigned)i);
        re[j] = v.x; im[j] = v.y;
    }
    __syncthreads();
#pragma unroll
    for (int s = 1; s <= 10; ++s) {
        const int half = 1 << (s - 1);
        const int m = half << 1;
#pragma unroll
        for (int r = 0; r < 2; ++r) {
            int bf = t + r * 256;
            int grp = bf >> (s - 1);
            int pos = bf & (half - 1);
            int i1 = grp * m + pos;
            int i2 = i1 + half;
            int ti = pos << (10 - s);
            float wr = twr[ti], wi = twi[ti];
            float xr2 = re[i2], xi2 = im[i2];
            float tr = wr * xr2 - wi * xi2;
            float tc = wr * xi2 + wi * xr2;
            float ur = re[i1], ui = im[i1];
            re[i1] = ur + tr; im[i1] = ui + tc;
            re[i2] = ur - tr; im[i2] = ui - tc;
        }
        __syncthreads();
    }
    float mmax = 0.0f;
    for (int k = t; k < 1024; k += 256) {
        float rr = re[k], ii = im[k];
        float mag = sqrtf(rr * rr + ii * ii);
        mmax = fmaxf(mmax, mag);
        float ph = atan2f(ii, rr);
        float pu = (ph < 0.0f) ? ph + TWO_PI_F : ph;
        base[(long long)k * WR].x = pu;
    }
#pragma unroll
    for (int off = 32; off; off >>= 1) mmax = fmaxf(mmax, __shfl_down(mmax, off));
    if ((t & 63) == 0) atomicMax((int*)(magmax + b), __float_as_int(mmax));
}

// ---------------------------------------------------------------------------
// Kernel C: per-pixel gradients + Zernike moments.
// Moments: M_c[p][a] = sum v*rho^p*cos(a*theta), M_s[p][a] = ... sin(...),
// for a <= p, a parity == p parity. 30 cos + 25 sin = 55 accumulators.
// ---------------------------------------------------------------------------
__global__ __launch_bounds__(256) void stats_kernel(const float2* __restrict__ rf,
                                                    float* __restrict__ acc,
                                                    float* __restrict__ maskcnt) {
    const int b = blockIdx.y;
    const float2* base = rf + (long long)b * HH * WR;
    float accm[55];
#pragma unroll
    for (int i = 0; i < 55; ++i) accm[i] = 0.0f;
    float sgx = 0.0f, sgx2 = 0.0f, sgy = 0.0f, sgy2 = 0.0f, cnt = 0.0f;
    const int stride = gridDim.x * blockDim.x;
    for (int idx = blockIdx.x * blockDim.x + threadIdx.x; idx < NPIX; idx += stride) {
        int h = idx / WR;
        int w = idx - h * WR;
        float v = base[idx].x;
        float gx, gy;
        if (w == 0)            gx = base[idx + 1].x - v;
        else if (w == WR - 1)  gx = v - base[idx - 1].x;
        else                   gx = 0.5f * (base[idx + 1].x - base[idx - 1].x);
        if (h == 0)            gy = base[idx + WR].x - v;
        else if (h == HH - 1)  gy = v - base[idx - WR].x;
        else                   gy = 0.5f * (base[idx + WR].x - base[idx - WR].x);
        sgx += gx; sgx2 += gx * gx; sgy += gy; sgy2 += gy * gy;

        float yv = -1.0f + (2.0f / 1023.0f) * (float)h;
        float xv = -1.0f + (1.0f / 256.0f) * (float)w;
        float r2 = xv * xv + yv * yv;
        if (r2 <= 1.0f) {
            cnt += 1.0f;
            float rho = sqrtf(r2);        // rho > 0 everywhere on this grid
            float inv = 1.0f / rho;
            float c1 = xv * inv, s1 = yv * inv;
            float vp[10];
            vp[0] = v;
#pragma unroll
            for (int p = 1; p < 10; ++p) vp[p] = vp[p - 1] * rho;
            float cm[10], sm[10];
            cm[0] = 1.0f; sm[0] = 0.0f;
            cm[1] = c1;   sm[1] = s1;
#pragma unroll
            for (int a = 2; a < 10; ++a) {
                cm[a] = cm[a - 1] * c1 - sm[a - 1] * s1;
                sm[a] = sm[a - 1] * c1 + cm[a - 1] * s1;
            }
            int ai = 0;
#pragma unroll
            for (int p = 0; p < 10; ++p)
#pragma unroll
                for (int a = (p & 1); a <= p; a += 2) { accm[ai] += vp[p] * cm[a]; ++ai; }
#pragma unroll
            for (int p = 1; p < 10; ++p)
#pragma unroll
                for (int a = ((p & 1) ? 1 : 2); a <= p; a += 2) { accm[ai] += vp[p] * sm[a]; ++ai; }
        }
    }
    float* ab = acc + b * 64;
    const bool lane0 = ((threadIdx.x & 63) == 0);
#pragma unroll
    for (int i = 0; i < 55; ++i) {
        float r = accm[i];
#pragma unroll
        for (int off = 32; off; off >>= 1) r += __shfl_down(r, off);
        if (lane0) atomicAdd(&ab[i], r);
    }
    {
        float r = sgx;
#pragma unroll
        for (int off = 32; off; off >>= 1) r += __shfl_down(r, off);
        if (lane0) atomicAdd(&ab[55], r);
        r = sgx2;
#pragma unroll
        for (int off = 32; off; off >>= 1) r += __shfl_down(r, off);
        if (lane0) atomicAdd(&ab[56], r);
        r = sgy;
#pragma unroll
        for (int off = 32; off; off >>= 1) r += __shfl_down(r, off);
        if (lane0) atomicAdd(&ab[57], r);
        r = sgy2;
#pragma unroll
        for (int off = 32; off; off >>= 1) r += __shfl_down(r, off);
        if (lane0) atomicAdd(&ab[58], r);
    }
    if (b == 0) {
        float r = cnt;
#pragma unroll
        for (int off = 32; off; off >>= 1) r += __shfl_down(r, off);
        if (lane0) atomicAdd(maskcnt, r);
    }
}

// ---------------------------------------------------------------------------
// Kernel D: map moments -> Zernike coefficients, finalize stats
// ---------------------------------------------------------------------------
__device__ int moment_index(int p, int a, int is_cos) {
    int ai = 0;
    for (int pp = 0; pp < 10; ++pp)
        for (int aa = (pp & 1); aa <= pp; aa += 2) {
            if (is_cos && pp == p && aa == a) return ai;
            ++ai;
        }
    for (int pp = 1; pp < 10; ++pp)
        for (int aa = ((pp & 1) ? 1 : 2); aa <= pp; aa += 2) {
            if (!is_cos && pp == p && aa == a) return ai;
            ++ai;
        }
    return 0;
}

__device__ float factf(int n) {
    float f = 1.0f;
    for (int i = 2; i <= n; ++i) f *= (float)i;
    return f;
}

__global__ void finalize_kernel(const float* __restrict__ acc,
                                const float* __restrict__ maskcnt,
                                const float* __restrict__ magmax,
                                float* __restrict__ out) {
    int b = blockIdx.x;
    int j = threadIdx.x;
    if (j >= 60) return;
    const float* ab = acc + b * 64;
    const float NF = (float)NPIX;
    float val;
    if (j < 55) {
        int tt = j, n = 0;
        while (tt >= n + 1) { tt -= (n + 1); ++n; }
        int m = -n + 2 * tt;
        int am = m < 0 ? -m : m;
        float s = 0.0f;
        for (int k = 0; k <= (n - am) / 2; ++k) {
            float c = factf(n - k) /
                      (factf(k) * factf((n + am) / 2 - k) * factf((n - am) / 2 - k));
            if (k & 1) c = -c;
            int p = n - 2 * k;
            s += c * ab[moment_index(p, am, m >= 0 ? 1 : 0)];
        }
        val = s / maskcnt[0];
    } else if (j == 55) {            // grad_x mean
        val = ab[55] / NF;
    } else if (j == 56) {            // grad_y mean
        val = ab[57] / NF;
    } else if (j == 57) {            // grad_x std (ddof=1)
        float sum = ab[55], sq = ab[56];
        val = sqrtf(fmaxf(0.0f, (sq - sum * sum / NF) / (NF - 1.0f)));
    } else if (j == 58) {            // grad_y std (ddof=1)
        float sum = ab[57], sq = ab[58];
        val = sqrtf(fmaxf(0.0f, (sq - sum * sum / NF) / (NF - 1.0f)));
    } else {                         // freq feature: max |FFT|
        val = magmax[b];
    }
    out[b * 60 + j] = val;
}

// ---------------------------------------------------------------------------
extern "C" void kernel_launch(void* const* d_in, const int* in_sizes, int n_in,
                              void* d_out, int out_size, void* d_ws, size_t ws_size,
                              hipStream_t stream) {
    (void)in_sizes; (void)n_in; (void)out_size; (void)ws_size;
    const float* x = (const float*)d_in[0];
    float* out = (float*)d_out;

    // ws layout: [acc 32*64 f][magmax 32 f][maskcnt 1 f] ... pad ... [rf complex buffer]
    float* acc = (float*)d_ws;
    float* magmax = acc + 32 * 64;
    float* maskcnt = magmax + 32;
    float2* rf = (float2*)((char*)d_ws + 16384);   // 32*1024*513 float2 = 134.5 MB

    hipMemsetAsync(d_ws, 0, 16384, stream);
    row_fft_kernel<<<BATCH * HH, 256, 0, stream>>>(x, rf);
    col_fft_kernel<<<BATCH * WR, 256, 0, stream>>>(rf, magmax);
    dim3 gridC(128, BATCH);
    stats_kernel<<<gridC, 256, 0, stream>>>(rf, acc, maskcnt);
    finalize_kernel<<<BATCH, 64, 0, stream>>>(acc, maskcnt, magmax, out);
}

// Round 2
// 1132.505 us; speedup vs baseline: 1.6420x; 1.6420x over previous
//
#include <hip/hip_runtime.h>
#include <math.h>

#define BATCH 32
#define HH 1024
#define WW 1024
#define WR 513
#define NPIX (HH * WR)
#define TWO_PI_F 6.28318530717958647692f

// LDS padding: +1 float2 per 16 elements keeps b64 accesses at the dense baseline
#define PAD(i) ((i) + ((i) >> 4))

__device__ __forceinline__ float2 cmul(float2 a, float2 b) {
    return make_float2(a.x * b.x - a.y * b.y, a.x * b.y + a.y * b.x);
}

// One Stockham radix-4 stage: out[j*4L+k+q*L] = sum_p in[t+p*256]*(-i)^{qp}*exp(-2pi*i*k*p/(4L))
template <int L>
__device__ __forceinline__ void fft_stage(const float2* __restrict__ src,
                                          float2* __restrict__ dst, int t) {
    const int k = t & (L - 1);
    const int j = t / L;
    float2 x0 = src[PAD(t)];
    float2 x1 = src[PAD(t + 256)];
    float2 x2 = src[PAD(t + 512)];
    float2 x3 = src[PAD(t + 768)];
    if (L > 1) {
        float s, c;
        __sincosf((-TWO_PI_F / (4.0f * (float)L)) * (float)k, &s, &c);
        float2 w1 = make_float2(c, s);
        float2 w2 = cmul(w1, w1);
        float2 w3 = cmul(w2, w1);
        x1 = cmul(x1, w1);
        x2 = cmul(x2, w2);
        x3 = cmul(x3, w3);
    }
    float2 a0 = make_float2(x0.x + x2.x, x0.y + x2.y);
    float2 a1 = make_float2(x0.x - x2.x, x0.y - x2.y);
    float2 a2 = make_float2(x1.x + x3.x, x1.y + x3.y);
    float2 a3 = make_float2(x1.x - x3.x, x1.y - x3.y);
    const int ob = j * (4 * L) + k;
    dst[PAD(ob)]         = make_float2(a0.x + a2.x, a0.y + a2.y);
    dst[PAD(ob + L)]     = make_float2(a1.x + a3.y, a1.y - a3.x);  // -i * a3
    dst[PAD(ob + 2 * L)] = make_float2(a0.x - a2.x, a0.y - a2.y);
    dst[PAD(ob + 3 * L)] = make_float2(a1.x - a3.y, a1.y + a3.x);  // +i * a3
}

// input in A (natural order, PAD indexing), output in B (natural order)
__device__ __forceinline__ void fft1024(float2* A, float2* B, int t) {
    __syncthreads();
    fft_stage<1>(A, B, t);   __syncthreads();
    fft_stage<4>(B, A, t);   __syncthreads();
    fft_stage<16>(A, B, t);  __syncthreads();
    fft_stage<64>(B, A, t);  __syncthreads();
    fft_stage<256>(A, B, t); __syncthreads();
}

// ---------------------------------------------------------------------------
// Kernel A: two real rows packed into one complex FFT; unpack via symmetry.
// ---------------------------------------------------------------------------
__global__ __launch_bounds__(256) void row_fft_kernel(const float* __restrict__ x,
                                                      float2* __restrict__ rf) {
    __shared__ float2 A[1088], B[1088];
    const int t = threadIdx.x;
    const int blk = blockIdx.x;          // b*512 + p
    const int b = blk >> 9;
    const int p = blk & 511;
    const float* r0 = x + ((long long)b * HH + 2 * p) * (long long)WW;
    const float* r1 = r0 + WW;
    for (int i = t; i < 1024; i += 256) A[PAD(i)] = make_float2(r0[i], r1[i]);
    fft1024(A, B, t);
    float2* o0 = rf + ((long long)b * HH + 2 * p) * (long long)WR;
    float2* o1 = o0 + WR;
    for (int k = t; k < WR; k += 256) {
        float2 zk = B[PAD(k)];
        float2 zn = B[PAD((1024 - k) & 1023)];
        // X0 = (Z[k] + conj(Z[N-k]))/2 ; X1 = -i(Z[k] - conj(Z[N-k]))/2
        o0[k] = make_float2(0.5f * (zk.x + zn.x), 0.5f * (zk.y - zn.y));
        o1[k] = make_float2(0.5f * (zk.y + zn.y), 0.5f * (zn.x - zk.x));
    }
}

// ---------------------------------------------------------------------------
// Kernel B: column FFT per (b,w); epilogue: magnitude max + unwrapped phase
// written in place into .x (column-private, race-free).
// ---------------------------------------------------------------------------
__global__ __launch_bounds__(256) void col_fft_kernel(float2* __restrict__ rf,
                                                      float* __restrict__ magmax) {
    __shared__ float2 A[1088], B[1088];
    const int t = threadIdx.x;
    const int c = blockIdx.x;
    const int b = c / WR;
    const int w = c - b * WR;
    float2* base = rf + (long long)b * HH * WR + w;
    for (int i = t; i < 1024; i += 256) A[PAD(i)] = base[(long long)i * WR];
    fft1024(A, B, t);
    float mmax = 0.0f;
    for (int k = t; k < 1024; k += 256) {
        float2 z = B[PAD(k)];
        float mag = sqrtf(z.x * z.x + z.y * z.y);
        mmax = fmaxf(mmax, mag);
        float ph = atan2f(z.y, z.x);
        base[(long long)k * WR].x = (ph < 0.0f) ? ph + TWO_PI_F : ph;
    }
#pragma unroll
    for (int off = 32; off; off >>= 1) mmax = fmaxf(mmax, __shfl_down(mmax, off));
    if ((t & 63) == 0) atomicMax((int*)(magmax + b), __float_as_int(mmax));
}

// ---------------------------------------------------------------------------
// Kernel C: per-pixel gradients + 55 Zernike moments. Row-structured loop
// (no per-pixel integer division); launch_bounds(256,1) so nothing spills.
// ---------------------------------------------------------------------------
__global__ __launch_bounds__(256, 1) void stats_kernel(const float2* __restrict__ rf,
                                                       float* __restrict__ acc,
                                                       float* __restrict__ maskcnt) {
    const int b = blockIdx.y;
    const int r0 = blockIdx.x * 32;     // 32 blocks of 32 rows each
    const float2* base = rf + (long long)b * HH * WR;
    float accm[55];
#pragma unroll
    for (int i = 0; i < 55; ++i) accm[i] = 0.0f;
    float sgx = 0.0f, sgx2 = 0.0f, sgy = 0.0f, sgy2 = 0.0f, cnt = 0.0f;

    for (int r = 0; r < 32; ++r) {
        const int h = r0 + r;
        const float2* row = base + (long long)h * WR;
        const float yv = -1.0f + (2.0f / 1023.0f) * (float)h;
        const float yv2 = yv * yv;
        for (int w = threadIdx.x; w < WR; w += 256) {
            float v = row[w].x;
            float gx, gy;
            if (w == 0)            gx = row[w + 1].x - v;
            else if (w == WR - 1)  gx = v - row[w - 1].x;
            else                   gx = 0.5f * (row[w + 1].x - row[w - 1].x);
            if (h == 0)            gy = row[w + WR].x - v;
            else if (h == HH - 1)  gy = v - row[w - WR].x;
            else                   gy = 0.5f * (row[w + WR].x - row[w - WR].x);
            sgx += gx; sgx2 += gx * gx; sgy += gy; sgy2 += gy * gy;

            const float xv = -1.0f + (1.0f / 256.0f) * (float)w;
            const float r2 = xv * xv + yv2;
            if (r2 <= 1.0f) {
                cnt += 1.0f;
                const float rho = sqrtf(r2);
                const float inv = rsqrtf(r2);
                const float c1 = xv * inv, s1 = yv * inv;
                float vp[10];
                vp[0] = v;
#pragma unroll
                for (int p = 1; p < 10; ++p) vp[p] = vp[p - 1] * rho;
                float cm[10], sm[10];
                cm[0] = 1.0f; sm[0] = 0.0f;
                cm[1] = c1;   sm[1] = s1;
#pragma unroll
                for (int a = 2; a < 10; ++a) {
                    cm[a] = cm[a - 1] * c1 - sm[a - 1] * s1;
                    sm[a] = sm[a - 1] * c1 + cm[a - 1] * s1;
                }
                int ai = 0;
#pragma unroll
                for (int p = 0; p < 10; ++p)
#pragma unroll
                    for (int a = (p & 1); a <= p; a += 2) { accm[ai] += vp[p] * cm[a]; ++ai; }
#pragma unroll
                for (int p = 1; p < 10; ++p)
#pragma unroll
                    for (int a = ((p & 1) ? 1 : 2); a <= p; a += 2) { accm[ai] += vp[p] * sm[a]; ++ai; }
            }
        }
    }

    float* ab = acc + b * 64;
    const bool lane0 = ((threadIdx.x & 63) == 0);
#pragma unroll
    for (int i = 0; i < 55; ++i) {
        float r = accm[i];
#pragma unroll
        for (int off = 32; off; off >>= 1) r += __shfl_down(r, off);
        if (lane0) atomicAdd(&ab[i], r);
    }
    {
        float r = sgx;
#pragma unroll
        for (int off = 32; off; off >>= 1) r += __shfl_down(r, off);
        if (lane0) atomicAdd(&ab[55], r);
        r = sgx2;
#pragma unroll
        for (int off = 32; off; off >>= 1) r += __shfl_down(r, off);
        if (lane0) atomicAdd(&ab[56], r);
        r = sgy;
#pragma unroll
        for (int off = 32; off; off >>= 1) r += __shfl_down(r, off);
        if (lane0) atomicAdd(&ab[57], r);
        r = sgy2;
#pragma unroll
        for (int off = 32; off; off >>= 1) r += __shfl_down(r, off);
        if (lane0) atomicAdd(&ab[58], r);
    }
    if (b == 0) {
        float r = cnt;
#pragma unroll
        for (int off = 32; off; off >>= 1) r += __shfl_down(r, off);
        if (lane0) atomicAdd(maskcnt, r);
    }
}

// ---------------------------------------------------------------------------
// Kernel D: map moments -> Zernike coefficients, finalize stats
// ---------------------------------------------------------------------------
__device__ int moment_index(int p, int a, int is_cos) {
    int ai = 0;
    for (int pp = 0; pp < 10; ++pp)
        for (int aa = (pp & 1); aa <= pp; aa += 2) {
            if (is_cos && pp == p && aa == a) return ai;
            ++ai;
        }
    for (int pp = 1; pp < 10; ++pp)
        for (int aa = ((pp & 1) ? 1 : 2); aa <= pp; aa += 2) {
            if (!is_cos && pp == p && aa == a) return ai;
            ++ai;
        }
    return 0;
}

__device__ float factf(int n) {
    float f = 1.0f;
    for (int i = 2; i <= n; ++i) f *= (float)i;
    return f;
}

__global__ void finalize_kernel(const float* __restrict__ acc,
                                const float* __restrict__ maskcnt,
                                const float* __restrict__ magmax,
                                float* __restrict__ out) {
    int b = blockIdx.x;
    int j = threadIdx.x;
    if (j >= 60) return;
    const float* ab = acc + b * 64;
    const float NF = (float)NPIX;
    float val;
    if (j < 55) {
        int tt = j, n = 0;
        while (tt >= n + 1) { tt -= (n + 1); ++n; }
        int m = -n + 2 * tt;
        int am = m < 0 ? -m : m;
        float s = 0.0f;
        for (int k = 0; k <= (n - am) / 2; ++k) {
            float c = factf(n - k) /
                      (factf(k) * factf((n + am) / 2 - k) * factf((n - am) / 2 - k));
            if (k & 1) c = -c;
            int p = n - 2 * k;
            s += c * ab[moment_index(p, am, m >= 0 ? 1 : 0)];
        }
        val = s / maskcnt[0];
    } else if (j == 55) {
        val = ab[55] / NF;
    } else if (j == 56) {
        val = ab[57] / NF;
    } else if (j == 57) {
        float sum = ab[55], sq = ab[56];
        val = sqrtf(fmaxf(0.0f, (sq - sum * sum / NF) / (NF - 1.0f)));
    } else if (j == 58) {
        float sum = ab[57], sq = ab[58];
        val = sqrtf(fmaxf(0.0f, (sq - sum * sum / NF) / (NF - 1.0f)));
    } else {
        val = magmax[b];
    }
    out[b * 60 + j] = val;
}

// ---------------------------------------------------------------------------
extern "C" void kernel_launch(void* const* d_in, const int* in_sizes, int n_in,
                              void* d_out, int out_size, void* d_ws, size_t ws_size,
                              hipStream_t stream) {
    (void)in_sizes; (void)n_in; (void)out_size; (void)ws_size;
    const float* x = (const float*)d_in[0];
    float* out = (float*)d_out;

    float* acc = (float*)d_ws;
    float* magmax = acc + 32 * 64;
    float* maskcnt = magmax + 32;
    float2* rf = (float2*)((char*)d_ws + 16384);   // 32*1024*513 float2 = 134.5 MB

    hipMemsetAsync(d_ws, 0, 16384, stream);
    row_fft_kernel<<<BATCH * (HH / 2), 256, 0, stream>>>(x, rf);
    col_fft_kernel<<<BATCH * WR, 256, 0, stream>>>(rf, magmax);
    dim3 gridC(32, BATCH);
    stats_kernel<<<gridC, 256, 0, stream>>>(rf, acc, maskcnt);
    finalize_kernel<<<BATCH, 64, 0, stream>>>(acc, maskcnt, magmax, out);
}

// Round 3
// 1123.769 us; speedup vs baseline: 1.6547x; 1.0078x over previous
//
#include <hip/hip_runtime.h>
#include <math.h>

#define BATCH 32
#define HH 1024
#define WW 1024
#define WR 513
#define NPIX (HH * WR)
#define TWO_PI_F 6.28318530717958647692f

// LDS padding: +1 float2 per 16 elements
#define PAD(i) ((i) + ((i) >> 4))

__device__ __forceinline__ float2 cmul(float2 a, float2 b) {
    return make_float2(a.x * b.x - a.y * b.y, a.x * b.y + a.y * b.x);
}

// Single-buffer radix-4 Stockham stage: read all -> sync -> write all -> sync.
template <int L>
__device__ __forceinline__ void fft_stage_ip(float2* buf, int t) {
    const int k = t & (L - 1);
    const int j = t / L;
    float2 x0 = buf[PAD(t)];
    float2 x1 = buf[PAD(t + 256)];
    float2 x2 = buf[PAD(t + 512)];
    float2 x3 = buf[PAD(t + 768)];
    __syncthreads();
    if (L > 1) {
        float s, c;
        __sincosf((-TWO_PI_F / (4.0f * (float)L)) * (float)k, &s, &c);
        float2 w1 = make_float2(c, s);
        float2 w2 = cmul(w1, w1);
        float2 w3 = cmul(w2, w1);
        x1 = cmul(x1, w1);
        x2 = cmul(x2, w2);
        x3 = cmul(x3, w3);
    }
    float2 a0 = make_float2(x0.x + x2.x, x0.y + x2.y);
    float2 a1 = make_float2(x0.x - x2.x, x0.y - x2.y);
    float2 a2 = make_float2(x1.x + x3.x, x1.y + x3.y);
    float2 a3 = make_float2(x1.x - x3.x, x1.y - x3.y);
    const int ob = j * (4 * L) + k;
    buf[PAD(ob)]         = make_float2(a0.x + a2.x, a0.y + a2.y);
    buf[PAD(ob + L)]     = make_float2(a1.x + a3.y, a1.y - a3.x);  // -i*a3
    buf[PAD(ob + 2 * L)] = make_float2(a0.x - a2.x, a0.y - a2.y);
    buf[PAD(ob + 3 * L)] = make_float2(a1.x - a3.y, a1.y + a3.x);  // +i*a3
    __syncthreads();
}

__device__ __forceinline__ void fft1024_ip(float2* A, int t) {
    __syncthreads();                 // after caller's fill of A
    fft_stage_ip<1>(A, t);
    fft_stage_ip<4>(A, t);
    fft_stage_ip<16>(A, t);
    fft_stage_ip<64>(A, t);
    fft_stage_ip<256>(A, t);
}

// ---------------------------------------------------------------------------
// Kernel A: 8 rows per block (4 packed real FFTs); output TRANSPOSED as
// rf2[b][k][h] via an LDS tile so global writes are 64B-contiguous in h.
// ---------------------------------------------------------------------------
__global__ __launch_bounds__(256) void row_fft_kernel(const float* __restrict__ x,
                                                      float2* __restrict__ rf2) {
    __shared__ float2 A[1088];          // 8.7 KB FFT working buffer
    __shared__ float2 O[513 * 9];       // 36.9 KB output tile, stride 9 (pad)
    const int t = threadIdx.x;
    const int b = blockIdx.x >> 7;                // 128 blocks per batch
    const int h0 = (blockIdx.x & 127) * 8;

    for (int p = 0; p < 4; ++p) {
        const float* r0 = x + ((long long)b * HH + h0 + 2 * p) * (long long)WW;
        const float* r1 = r0 + WW;
        for (int i = t; i < 1024; i += 256) A[PAD(i)] = make_float2(r0[i], r1[i]);
        fft1024_ip(A, t);
        for (int k = t; k <= 512; k += 256) {
            float2 zk = A[PAD(k)];
            float2 zn = A[PAD((1024 - k) & 1023)];
            // X0 = (Z[k]+conj(Z[N-k]))/2 ; X1 = -i(Z[k]-conj(Z[N-k]))/2
            O[k * 9 + 2 * p]     = make_float2(0.5f * (zk.x + zn.x), 0.5f * (zk.y - zn.y));
            O[k * 9 + 2 * p + 1] = make_float2(0.5f * (zk.y + zn.y), 0.5f * (zn.x - zk.x));
        }
        __syncthreads();                // protect A before next fill, O before write
    }
    for (int idx = t; idx < 513 * 8; idx += 256) {
        int k = idx >> 3, j = idx & 7;
        rf2[((long long)b * WR + k) * 1024 + h0 + j] = O[k * 9 + j];
    }
}

// ---------------------------------------------------------------------------
// Kernel B: column FFT = contiguous 8KB row of rf2[b][k][:]. Epilogue:
// magnitude max + unwrapped phase written in place as compact floats over
// the block's own row (4KB contiguous, race-free).
// ---------------------------------------------------------------------------
__global__ __launch_bounds__(256) void col_fft_kernel(float2* __restrict__ rf2,
                                                      float* __restrict__ magmax) {
    __shared__ float2 A[1088];
    const int t = threadIdx.x;
    const int c = blockIdx.x;
    const int b = c / WR;
    const int k = c - b * WR;
    float2* row = rf2 + ((long long)b * WR + k) * 1024;
    for (int i = t; i < 1024; i += 256) A[PAD(i)] = row[i];
    fft1024_ip(A, t);
    float* pu = (float*)row;
    float mmax = 0.0f;
    for (int h = t; h < 1024; h += 256) {
        float2 z = A[PAD(h)];
        float mag = sqrtf(z.x * z.x + z.y * z.y);
        mmax = fmaxf(mmax, mag);
        float ph = atan2f(z.y, z.x);
        pu[h] = (ph < 0.0f) ? ph + TWO_PI_F : ph;
    }
#pragma unroll
    for (int off = 32; off; off >>= 1) mmax = fmaxf(mmax, __shfl_down(mmax, off));
    if ((t & 63) == 0) atomicMax((int*)(magmax + b), __float_as_int(mmax));
}

// ---------------------------------------------------------------------------
// Kernel C: gradients + 55 Zernike moments on the transposed phase map.
// pu rows are k-major (stride 2048 floats); h is contiguous.
// gx = gradient along k, gy = gradient along h.
// ---------------------------------------------------------------------------
__global__ __launch_bounds__(256, 1) void stats_kernel(const float* __restrict__ pu,
                                                       float* __restrict__ acc,
                                                       float* __restrict__ maskcnt) {
    const int b = blockIdx.y;
    const int k0 = blockIdx.x * 9;      // 57 blocks x 9 k-rows = 513
    const float* base = pu + (long long)b * WR * 2048;
    float accm[55];
#pragma unroll
    for (int i = 0; i < 55; ++i) accm[i] = 0.0f;
    float sgx = 0.0f, sgx2 = 0.0f, sgy = 0.0f, sgy2 = 0.0f, cnt = 0.0f;

    for (int kk = 0; kk < 9; ++kk) {
        const int k = k0 + kk;
        const float* rowc = base + (long long)k * 2048;
        const float* rowm = rowc - 2048;
        const float* rowp = rowc + 2048;
        const float xv = -1.0f + (1.0f / 256.0f) * (float)k;
        const float xv2 = xv * xv;
        for (int h = threadIdx.x; h < 1024; h += 256) {
            float v = rowc[h];
            float gx, gy;
            if (k == 0)            gx = rowp[h] - v;
            else if (k == WR - 1)  gx = v - rowm[h];
            else                   gx = 0.5f * (rowp[h] - rowm[h]);
            if (h == 0)            gy = rowc[1] - v;
            else if (h == 1023)    gy = v - rowc[1022];
            else                   gy = 0.5f * (rowc[h + 1] - rowc[h - 1]);
            sgx += gx; sgx2 += gx * gx; sgy += gy; sgy2 += gy * gy;

            const float yv = -1.0f + (2.0f / 1023.0f) * (float)h;
            const float r2 = xv2 + yv * yv;
            if (r2 <= 1.0f) {
                cnt += 1.0f;
                const float rho = sqrtf(r2);
                const float inv = rsqrtf(r2);
                const float c1 = xv * inv, s1 = yv * inv;
                float vp[10];
                vp[0] = v;
#pragma unroll
                for (int p = 1; p < 10; ++p) vp[p] = vp[p - 1] * rho;
                float cm[10], sm[10];
                cm[0] = 1.0f; sm[0] = 0.0f;
                cm[1] = c1;   sm[1] = s1;
#pragma unroll
                for (int a = 2; a < 10; ++a) {
                    cm[a] = cm[a - 1] * c1 - sm[a - 1] * s1;
                    sm[a] = sm[a - 1] * c1 + cm[a - 1] * s1;
                }
                int ai = 0;
#pragma unroll
                for (int p = 0; p < 10; ++p)
#pragma unroll
                    for (int a = (p & 1); a <= p; a += 2) { accm[ai] += vp[p] * cm[a]; ++ai; }
#pragma unroll
                for (int p = 1; p < 10; ++p)
#pragma unroll
                    for (int a = ((p & 1) ? 1 : 2); a <= p; a += 2) { accm[ai] += vp[p] * sm[a]; ++ai; }
            }
        }
    }

    float* ab = acc + b * 64;
    const bool lane0 = ((threadIdx.x & 63) == 0);
#pragma unroll
    for (int i = 0; i < 55; ++i) {
        float r = accm[i];
#pragma unroll
        for (int off = 32; off; off >>= 1) r += __shfl_down(r, off);
        if (lane0) atomicAdd(&ab[i], r);
    }
    {
        float r = sgx;
#pragma unroll
        for (int off = 32; off; off >>= 1) r += __shfl_down(r, off);
        if (lane0) atomicAdd(&ab[55], r);
        r = sgx2;
#pragma unroll
        for (int off = 32; off; off >>= 1) r += __shfl_down(r, off);
        if (lane0) atomicAdd(&ab[56], r);
        r = sgy;
#pragma unroll
        for (int off = 32; off; off >>= 1) r += __shfl_down(r, off);
        if (lane0) atomicAdd(&ab[57], r);
        r = sgy2;
#pragma unroll
        for (int off = 32; off; off >>= 1) r += __shfl_down(r, off);
        if (lane0) atomicAdd(&ab[58], r);
    }
    if (b == 0) {
        float r = cnt;
#pragma unroll
        for (int off = 32; off; off >>= 1) r += __shfl_down(r, off);
        if (lane0) atomicAdd(maskcnt, r);
    }
}

// ---------------------------------------------------------------------------
// Kernel D: map moments -> Zernike coefficients, finalize stats
// ---------------------------------------------------------------------------
__device__ int moment_index(int p, int a, int is_cos) {
    int ai = 0;
    for (int pp = 0; pp < 10; ++pp)
        for (int aa = (pp & 1); aa <= pp; aa += 2) {
            if (is_cos && pp == p && aa == a) return ai;
            ++ai;
        }
    for (int pp = 1; pp < 10; ++pp)
        for (int aa = ((pp & 1) ? 1 : 2); aa <= pp; aa += 2) {
            if (!is_cos && pp == p && aa == a) return ai;
            ++ai;
        }
    return 0;
}

__device__ float factf(int n) {
    float f = 1.0f;
    for (int i = 2; i <= n; ++i) f *= (float)i;
    return f;
}

__global__ void finalize_kernel(const float* __restrict__ acc,
                                const float* __restrict__ maskcnt,
                                const float* __restrict__ magmax,
                                float* __restrict__ out) {
    int b = blockIdx.x;
    int j = threadIdx.x;
    if (j >= 60) return;
    const float* ab = acc + b * 64;
    const float NF = (float)NPIX;
    float val;
    if (j < 55) {
        int tt = j, n = 0;
        while (tt >= n + 1) { tt -= (n + 1); ++n; }
        int m = -n + 2 * tt;
        int am = m < 0 ? -m : m;
        float s = 0.0f;
        for (int k = 0; k <= (n - am) / 2; ++k) {
            float c = factf(n - k) /
                      (factf(k) * factf((n + am) / 2 - k) * factf((n - am) / 2 - k));
            if (k & 1) c = -c;
            int p = n - 2 * k;
            s += c * ab[moment_index(p, am, m >= 0 ? 1 : 0)];
        }
        val = s / maskcnt[0];
    } else if (j == 55) {
        val = ab[55] / NF;
    } else if (j == 56) {
        val = ab[57] / NF;
    } else if (j == 57) {
        float sum = ab[55], sq = ab[56];
        val = sqrtf(fmaxf(0.0f, (sq - sum * sum / NF) / (NF - 1.0f)));
    } else if (j == 58) {
        float sum = ab[57], sq = ab[58];
        val = sqrtf(fmaxf(0.0f, (sq - sum * sum / NF) / (NF - 1.0f)));
    } else {
        val = magmax[b];
    }
    out[b * 60 + j] = val;
}

// ---------------------------------------------------------------------------
extern "C" void kernel_launch(void* const* d_in, const int* in_sizes, int n_in,
                              void* d_out, int out_size, void* d_ws, size_t ws_size,
                              hipStream_t stream) {
    (void)in_sizes; (void)n_in; (void)out_size; (void)ws_size;
    const float* x = (const float*)d_in[0];
    float* out = (float*)d_out;

    float* acc = (float*)d_ws;
    float* magmax = acc + 32 * 64;
    float* maskcnt = magmax + 32;
    float2* rf2 = (float2*)((char*)d_ws + 16384);  // [B][WR][H] float2 = 134.5 MB

    hipMemsetAsync(d_ws, 0, 16384, stream);
    row_fft_kernel<<<BATCH * 128, 256, 0, stream>>>(x, rf2);
    col_fft_kernel<<<BATCH * WR, 256, 0, stream>>>(rf2, magmax);
    dim3 gridC(57, BATCH);
    stats_kernel<<<gridC, 256, 0, stream>>>((const float*)rf2, acc, maskcnt);
    finalize_kernel<<<BATCH, 64, 0, stream>>>(acc, maskcnt, magmax, out);
}

// Round 4
// 717.611 us; speedup vs baseline: 2.5913x; 1.5660x over previous
//
#include <hip/hip_runtime.h>
#include <math.h>

#define BATCH 32
#define HH 1024
#define WW 1024
#define WR 513
#define NPIX (HH * WR)
#define TWO_PI_F 6.28318530717958647692f

__device__ __forceinline__ float2 cadd(float2 a, float2 b) { return make_float2(a.x + b.x, a.y + b.y); }
__device__ __forceinline__ float2 csub(float2 a, float2 b) { return make_float2(a.x - b.x, a.y - b.y); }
__device__ __forceinline__ float2 cmul(float2 a, float2 b) {
    return make_float2(a.x * b.x - a.y * b.y, a.x * b.y + a.y * b.x);
}

// Natural-order 16-point FFT, in place, fully in registers (Stockham radix-4 x2).
__device__ __forceinline__ void fft16(float2* d) {
    float2 b[16];
#pragma unroll
    for (int t = 0; t < 4; ++t) {          // stage L=1: read d[t+4p] -> write b[4t+q]
        float2 x0 = d[t], x1 = d[t + 4], x2 = d[t + 8], x3 = d[t + 12];
        float2 a0 = cadd(x0, x2), a1 = csub(x0, x2), a2 = cadd(x1, x3), a3 = csub(x1, x3);
        b[4 * t + 0] = cadd(a0, a2);
        b[4 * t + 1] = make_float2(a1.x + a3.y, a1.y - a3.x);   // a1 + (-i)a3
        b[4 * t + 2] = csub(a0, a2);
        b[4 * t + 3] = make_float2(a1.x - a3.y, a1.y + a3.x);   // a1 + (+i)a3
    }
    const float2 W1[4] = {make_float2(1.0f, 0.0f),
                          make_float2(0.92387953f, -0.38268343f),
                          make_float2(0.70710678f, -0.70710678f),
                          make_float2(0.38268343f, -0.92387953f)};
#pragma unroll
    for (int t = 0; t < 4; ++t) {          // stage L=4: k=t: read b[t+4p]*W16^{tp} -> d[t+4q]
        float2 w1 = W1[t], w2 = cmul(w1, w1), w3 = cmul(w2, w1);
        float2 x0 = b[t], x1 = cmul(b[t + 4], w1), x2 = cmul(b[t + 8], w2), x3 = cmul(b[t + 12], w3);
        float2 a0 = cadd(x0, x2), a1 = csub(x0, x2), a2 = cadd(x1, x3), a3 = csub(x1, x3);
        d[t + 0]  = cadd(a0, a2);
        d[t + 4]  = make_float2(a1.x + a3.y, a1.y - a3.x);
        d[t + 8]  = csub(a0, a2);
        d[t + 12] = make_float2(a1.x - a3.y, a1.y + a3.x);
    }
}

// Wave-level 1024-pt FFT. Input: v[j] = x[lane + 64*j]. buf = this wave's 1088-float2 LDS.
// Output: v[m] = X[(lane&15) + 16*m + 256*kq], kq = 2*((lane>>4)&1) + ((lane>>5)&1).
// Exactly 2 __syncthreads (around the single LDS transpose).
__device__ __forceinline__ void wave_fft1024(float2* v, float2* buf, int lane) {
    fft16(v);                                           // FFT-16 over j -> k2
    float s, c;
    __sincosf(-TWO_PI_F * (float)lane * (1.0f / 1024.0f), &s, &c);
    float2 T = make_float2(c, s), w = T;
#pragma unroll
    for (int k2 = 1; k2 < 16; ++k2) { v[k2] = cmul(v[k2], w); w = cmul(w, T); }
    // LDS transpose: flat = 68*k2 + n1  (write contiguous; read bank-balanced)
#pragma unroll
    for (int k2 = 0; k2 < 16; ++k2) buf[68 * k2 + lane] = v[k2];
    __syncthreads();
    const int k2p = lane & 15, qp = lane >> 4;
#pragma unroll
    for (int m = 0; m < 16; ++m) v[m] = buf[68 * k2p + 4 * m + qp];
    __syncthreads();
    fft16(v);                                           // FFT-16 over m -> km
    __sincosf(-TWO_PI_F * (float)qp * (1.0f / 64.0f), &s, &c);
    float2 U = make_float2(c, s);
    w = U;
#pragma unroll
    for (int km = 1; km < 16; ++km) { v[km] = cmul(v[km], w); w = cmul(w, U); }
    // cross-lane DFT-4 over q (lane bits 4,5) via shfl_xor; output kq bit-reversed
    const bool hi2 = (lane & 32) != 0, hi1 = (lane & 16) != 0;
#pragma unroll
    for (int m = 0; m < 16; ++m) {
        float2 a = v[m];
        float2 o = make_float2(__shfl_xor(a.x, 32, 64), __shfl_xor(a.y, 32, 64));
        float2 s1 = hi2 ? csub(o, a) : cadd(a, o);
        if (hi2 && hi1) s1 = make_float2(s1.y, -s1.x);  // * -i
        float2 o2 = make_float2(__shfl_xor(s1.x, 16, 64), __shfl_xor(s1.y, 16, 64));
        v[m] = hi1 ? csub(o2, s1) : cadd(s1, o2);
    }
}

// ---------------------------------------------------------------------------
// Kernel A: 4 waves/block, each wave = 2 packed real rows -> 1 complex FFT.
// Unpack into LDS by k, then block-wide coalesced transposed flush to rf2[b][k][h].
// ---------------------------------------------------------------------------
__global__ __launch_bounds__(256, 4) void row_fft_kernel(const float* __restrict__ x,
                                                         float2* __restrict__ rf2) {
    __shared__ float2 buf[4 * 1088];
    const int t = threadIdx.x, w = t >> 6, lane = t & 63;
    const int b = blockIdx.x >> 7;
    const int h0 = (blockIdx.x & 127) * 8;
    const float* r0 = x + ((long long)b * HH + h0 + 2 * w) * (long long)WW;
    const float* r1 = r0 + WW;
    float2 v[16];
#pragma unroll
    for (int j = 0; j < 16; ++j) v[j] = make_float2(r0[lane + 64 * j], r1[lane + 64 * j]);
    float2* mybuf = buf + w * 1088;
    wave_fft1024(v, mybuf, lane);
    // scatter Z into mybuf indexed by k (same-wave LDS reuse is ordered; barrier below)
    const int kq = 2 * ((lane >> 4) & 1) + ((lane >> 5) & 1);
    const int kbase = (lane & 15) + 256 * kq;
#pragma unroll
    for (int m = 0; m < 16; ++m) mybuf[kbase + 16 * m] = v[m];
    __syncthreads();
    // unpack rfft pair + transposed flush (64B-contiguous global writes)
    for (int idx = t; idx < 513 * 8; idx += 256) {
        int k = idx >> 3, j = idx & 7, p = j >> 1, which = j & 1;
        float2 zk = buf[p * 1088 + k];
        float2 zn = buf[p * 1088 + ((1024 - k) & 1023)];
        float2 val = which ? make_float2(0.5f * (zk.y + zn.y), 0.5f * (zn.x - zk.x))
                           : make_float2(0.5f * (zk.x + zn.x), 0.5f * (zk.y - zn.y));
        rf2[((long long)b * WR + k) * 1024 + h0 + j] = val;
    }
}

// ---------------------------------------------------------------------------
// Kernel B: 2 waves/block, each wave = one contiguous 8KB row FFT of rf2[b][k][:].
// Epilogue: magnitude max + unwrapped phase written in place as floats.
// ---------------------------------------------------------------------------
__global__ __launch_bounds__(128, 4) void col_fft_kernel(float2* __restrict__ rf2,
                                                         float* __restrict__ magmax) {
    __shared__ float2 buf[2 * 1088];
    const int t = threadIdx.x, w = t >> 6, lane = t & 63;
    const int fid = blockIdx.x * 2 + w;       // 0 .. 16415
    const int b = fid / WR, k = fid - b * WR;
    float2* row = rf2 + ((long long)b * WR + k) * 1024;
    float2 v[16];
#pragma unroll
    for (int j = 0; j < 16; ++j) v[j] = row[lane + 64 * j];
    wave_fft1024(v, buf + w * 1088, lane);
    float* pu = (float*)row;
    const int kq = 2 * ((lane >> 4) & 1) + ((lane >> 5) & 1);
    const int hbase = (lane & 15) + 256 * kq;
    float mmax = 0.0f;
#pragma unroll
    for (int m = 0; m < 16; ++m) {
        float2 z = v[m];
        mmax = fmaxf(mmax, sqrtf(z.x * z.x + z.y * z.y));
        float ph = atan2f(z.y, z.x);
        pu[hbase + 16 * m] = (ph < 0.0f) ? ph + TWO_PI_F : ph;
    }
#pragma unroll
    for (int off = 32; off; off >>= 1) mmax = fmaxf(mmax, __shfl_down(mmax, off));
    if (lane == 0) atomicMax((int*)(magmax + b), __float_as_int(mmax));
}

// ---------------------------------------------------------------------------
// Kernel C: gradients + 55 Zernike moments on the transposed phase map.
// pu rows are k-major (stride 2048 floats); h contiguous.
// ---------------------------------------------------------------------------
__global__ __launch_bounds__(256, 1) void stats_kernel(const float* __restrict__ pu,
                                                       float* __restrict__ acc,
                                                       float* __restrict__ maskcnt) {
    const int b = blockIdx.y;
    const int k0 = blockIdx.x * 9;
    const float* base = pu + (long long)b * WR * 2048;
    float accm[55];
#pragma unroll
    for (int i = 0; i < 55; ++i) accm[i] = 0.0f;
    float sgx = 0.0f, sgx2 = 0.0f, sgy = 0.0f, sgy2 = 0.0f, cnt = 0.0f;

    for (int kk = 0; kk < 9; ++kk) {
        const int k = k0 + kk;
        const float* rowc = base + (long long)k * 2048;
        const float* rowm = rowc - 2048;
        const float* rowp = rowc + 2048;
        const float xv = -1.0f + (1.0f / 256.0f) * (float)k;
        const float xv2 = xv * xv;
        for (int h = threadIdx.x; h < 1024; h += 256) {
            float v = rowc[h];
            float gx, gy;
            if (k == 0)            gx = rowp[h] - v;
            else if (k == WR - 1)  gx = v - rowm[h];
            else                   gx = 0.5f * (rowp[h] - rowm[h]);
            if (h == 0)            gy = rowc[1] - v;
            else if (h == 1023)    gy = v - rowc[1022];
            else                   gy = 0.5f * (rowc[h + 1] - rowc[h - 1]);
            sgx += gx; sgx2 += gx * gx; sgy += gy; sgy2 += gy * gy;

            const float yv = -1.0f + (2.0f / 1023.0f) * (float)h;
            const float r2 = xv2 + yv * yv;
            if (r2 <= 1.0f) {
                cnt += 1.0f;
                const float rho = sqrtf(r2);
                const float inv = rsqrtf(r2);
                const float c1 = xv * inv, s1 = yv * inv;
                float vp[10];
                vp[0] = v;
#pragma unroll
                for (int p = 1; p < 10; ++p) vp[p] = vp[p - 1] * rho;
                float cm[10], sm[10];
                cm[0] = 1.0f; sm[0] = 0.0f;
                cm[1] = c1;   sm[1] = s1;
#pragma unroll
                for (int a = 2; a < 10; ++a) {
                    cm[a] = cm[a - 1] * c1 - sm[a - 1] * s1;
                    sm[a] = sm[a - 1] * c1 + cm[a - 1] * s1;
                }
                int ai = 0;
#pragma unroll
                for (int p = 0; p < 10; ++p)
#pragma unroll
                    for (int a = (p & 1); a <= p; a += 2) { accm[ai] += vp[p] * cm[a]; ++ai; }
#pragma unroll
                for (int p = 1; p < 10; ++p)
#pragma unroll
                    for (int a = ((p & 1) ? 1 : 2); a <= p; a += 2) { accm[ai] += vp[p] * sm[a]; ++ai; }
            }
        }
    }

    float* ab = acc + b * 64;
    const bool lane0 = ((threadIdx.x & 63) == 0);
#pragma unroll
    for (int i = 0; i < 55; ++i) {
        float r = accm[i];
#pragma unroll
        for (int off = 32; off; off >>= 1) r += __shfl_down(r, off);
        if (lane0) atomicAdd(&ab[i], r);
    }
    {
        float r = sgx;
#pragma unroll
        for (int off = 32; off; off >>= 1) r += __shfl_down(r, off);
        if (lane0) atomicAdd(&ab[55], r);
        r = sgx2;
#pragma unroll
        for (int off = 32; off; off >>= 1) r += __shfl_down(r, off);
        if (lane0) atomicAdd(&ab[56], r);
        r = sgy;
#pragma unroll
        for (int off = 32; off; off >>= 1) r += __shfl_down(r, off);
        if (lane0) atomicAdd(&ab[57], r);
        r = sgy2;
#pragma unroll
        for (int off = 32; off; off >>= 1) r += __shfl_down(r, off);
        if (lane0) atomicAdd(&ab[58], r);
    }
    if (b == 0) {
        float r = cnt;
#pragma unroll
        for (int off = 32; off; off >>= 1) r += __shfl_down(r, off);
        if (lane0) atomicAdd(maskcnt, r);
    }
}

// ---------------------------------------------------------------------------
// Kernel D: map moments -> Zernike coefficients, finalize stats
// ---------------------------------------------------------------------------
__device__ int moment_index(int p, int a, int is_cos) {
    int ai = 0;
    for (int pp = 0; pp < 10; ++pp)
        for (int aa = (pp & 1); aa <= pp; aa += 2) {
            if (is_cos && pp == p && aa == a) return ai;
            ++ai;
        }
    for (int pp = 1; pp < 10; ++pp)
        for (int aa = ((pp & 1) ? 1 : 2); aa <= pp; aa += 2) {
            if (!is_cos && pp == p && aa == a) return ai;
            ++ai;
        }
    return 0;
}

__device__ float factf(int n) {
    float f = 1.0f;
    for (int i = 2; i <= n; ++i) f *= (float)i;
    return f;
}

__global__ void finalize_kernel(const float* __restrict__ acc,
                                const float* __restrict__ maskcnt,
                                const float* __restrict__ magmax,
                                float* __restrict__ out) {
    int b = blockIdx.x;
    int j = threadIdx.x;
    if (j >= 60) return;
    const float* ab = acc + b * 64;
    const float NF = (float)NPIX;
    float val;
    if (j < 55) {
        int tt = j, n = 0;
        while (tt >= n + 1) { tt -= (n + 1); ++n; }
        int m = -n + 2 * tt;
        int am = m < 0 ? -m : m;
        float s = 0.0f;
        for (int k = 0; k <= (n - am) / 2; ++k) {
            float c = factf(n - k) /
                      (factf(k) * factf((n + am) / 2 - k) * factf((n - am) / 2 - k));
            if (k & 1) c = -c;
            int p = n - 2 * k;
            s += c * ab[moment_index(p, am, m >= 0 ? 1 : 0)];
        }
        val = s / maskcnt[0];
    } else if (j == 55) {
        val = ab[55] / NF;
    } else if (j == 56) {
        val = ab[57] / NF;
    } else if (j == 57) {
        float sum = ab[55], sq = ab[56];
        val = sqrtf(fmaxf(0.0f, (sq - sum * sum / NF) / (NF - 1.0f)));
    } else if (j == 58) {
        float sum = ab[57], sq = ab[58];
        val = sqrtf(fmaxf(0.0f, (sq - sum * sum / NF) / (NF - 1.0f)));
    } else {
        val = magmax[b];
    }
    out[b * 60 + j] = val;
}

// ---------------------------------------------------------------------------
extern "C" void kernel_launch(void* const* d_in, const int* in_sizes, int n_in,
                              void* d_out, int out_size, void* d_ws, size_t ws_size,
                              hipStream_t stream) {
    (void)in_sizes; (void)n_in; (void)out_size; (void)ws_size;
    const float* x = (const float*)d_in[0];
    float* out = (float*)d_out;

    float* acc = (float*)d_ws;
    float* magmax = acc + 32 * 64;
    float* maskcnt = magmax + 32;
    float2* rf2 = (float2*)((char*)d_ws + 16384);  // [B][WR][H] float2 = 134.5 MB

    hipMemsetAsync(d_ws, 0, 16384, stream);
    row_fft_kernel<<<BATCH * 128, 256, 0, stream>>>(x, rf2);
    col_fft_kernel<<<(BATCH * WR) / 2, 128, 0, stream>>>(rf2, magmax);
    dim3 gridC(57, BATCH);
    stats_kernel<<<gridC, 256, 0, stream>>>((const float*)rf2, acc, maskcnt);
    finalize_kernel<<<BATCH, 64, 0, stream>>>(acc, maskcnt, magmax, out);
}

// Round 5
// 699.559 us; speedup vs baseline: 2.6582x; 1.0258x over previous
//
#include <hip/hip_runtime.h>
#include <math.h>

#define BATCH 32
#define HH 1024
#define WW 1024
#define WR 513
#define NPIX (HH * WR)
#define TWO_PI_F 6.28318530717958647692f

__device__ __forceinline__ float2 cadd(float2 a, float2 b) { return make_float2(a.x + b.x, a.y + b.y); }
__device__ __forceinline__ float2 csub(float2 a, float2 b) { return make_float2(a.x - b.x, a.y - b.y); }
__device__ __forceinline__ float2 cmul(float2 a, float2 b) {
    return make_float2(a.x * b.x - a.y * b.y, a.x * b.y + a.y * b.x);
}

// Natural-order 16-point FFT, in place, fully in registers (Stockham radix-4 x2).
__device__ __forceinline__ void fft16(float2* d) {
    float2 b[16];
#pragma unroll
    for (int t = 0; t < 4; ++t) {
        float2 x0 = d[t], x1 = d[t + 4], x2 = d[t + 8], x3 = d[t + 12];
        float2 a0 = cadd(x0, x2), a1 = csub(x0, x2), a2 = cadd(x1, x3), a3 = csub(x1, x3);
        b[4 * t + 0] = cadd(a0, a2);
        b[4 * t + 1] = make_float2(a1.x + a3.y, a1.y - a3.x);
        b[4 * t + 2] = csub(a0, a2);
        b[4 * t + 3] = make_float2(a1.x - a3.y, a1.y + a3.x);
    }
    const float2 W1[4] = {make_float2(1.0f, 0.0f),
                          make_float2(0.92387953f, -0.38268343f),
                          make_float2(0.70710678f, -0.70710678f),
                          make_float2(0.38268343f, -0.92387953f)};
#pragma unroll
    for (int t = 0; t < 4; ++t) {
        float2 w1 = W1[t], w2 = cmul(w1, w1), w3 = cmul(w2, w1);
        float2 x0 = b[t], x1 = cmul(b[t + 4], w1), x2 = cmul(b[t + 8], w2), x3 = cmul(b[t + 12], w3);
        float2 a0 = cadd(x0, x2), a1 = csub(x0, x2), a2 = cadd(x1, x3), a3 = csub(x1, x3);
        d[t + 0]  = cadd(a0, a2);
        d[t + 4]  = make_float2(a1.x + a3.y, a1.y - a3.x);
        d[t + 8]  = csub(a0, a2);
        d[t + 12] = make_float2(a1.x - a3.y, a1.y + a3.x);
    }
}

// Wave-level 1024-pt FFT. Input: v[j] = x[lane + 64*j]. buf = this wave's 1088-float2 LDS.
// Output: v[m] = X[(lane&15) + 16*m + 256*kq], kq = 2*((lane>>4)&1) + ((lane>>5)&1).
__device__ __forceinline__ void wave_fft1024(float2* v, float2* buf, int lane) {
    fft16(v);
    float s, c;
    __sincosf(-TWO_PI_F * (float)lane * (1.0f / 1024.0f), &s, &c);
    float2 T = make_float2(c, s), w = T;
#pragma unroll
    for (int k2 = 1; k2 < 16; ++k2) { v[k2] = cmul(v[k2], w); w = cmul(w, T); }
#pragma unroll
    for (int k2 = 0; k2 < 16; ++k2) buf[68 * k2 + lane] = v[k2];
    __syncthreads();
    const int k2p = lane & 15, qp = lane >> 4;
#pragma unroll
    for (int m = 0; m < 16; ++m) v[m] = buf[68 * k2p + 4 * m + qp];
    __syncthreads();
    fft16(v);
    __sincosf(-TWO_PI_F * (float)qp * (1.0f / 64.0f), &s, &c);
    float2 U = make_float2(c, s);
    w = U;
#pragma unroll
    for (int km = 1; km < 16; ++km) { v[km] = cmul(v[km], w); w = cmul(w, U); }
    const bool hi2 = (lane & 32) != 0, hi1 = (lane & 16) != 0;
#pragma unroll
    for (int m = 0; m < 16; ++m) {
        float2 a = v[m];
        float2 o = make_float2(__shfl_xor(a.x, 32, 64), __shfl_xor(a.y, 32, 64));
        float2 s1 = hi2 ? csub(o, a) : cadd(a, o);
        if (hi2 && hi1) s1 = make_float2(s1.y, -s1.x);
        float2 o2 = make_float2(__shfl_xor(s1.x, 16, 64), __shfl_xor(s1.y, 16, 64));
        v[m] = hi1 ? csub(o2, s1) : cadd(s1, o2);
    }
}

// ---------------------------------------------------------------------------
// Kernel A: 4 waves/block, each wave = 2 packed real rows -> 1 complex FFT.
// ---------------------------------------------------------------------------
__global__ __launch_bounds__(256, 4) void row_fft_kernel(const float* __restrict__ x,
                                                         float2* __restrict__ rf2) {
    __shared__ float2 buf[4 * 1088];
    const int t = threadIdx.x, w = t >> 6, lane = t & 63;
    const int b = blockIdx.x >> 7;
    const int h0 = (blockIdx.x & 127) * 8;
    const float* r0 = x + ((long long)b * HH + h0 + 2 * w) * (long long)WW;
    const float* r1 = r0 + WW;
    float2 v[16];
#pragma unroll
    for (int j = 0; j < 16; ++j) v[j] = make_float2(r0[lane + 64 * j], r1[lane + 64 * j]);
    float2* mybuf = buf + w * 1088;
    wave_fft1024(v, mybuf, lane);
    const int kq = 2 * ((lane >> 4) & 1) + ((lane >> 5) & 1);
    const int kbase = (lane & 15) + 256 * kq;
#pragma unroll
    for (int m = 0; m < 16; ++m) mybuf[kbase + 16 * m] = v[m];
    __syncthreads();
    for (int idx = t; idx < 513 * 8; idx += 256) {
        int k = idx >> 3, j = idx & 7, p = j >> 1, which = j & 1;
        float2 zk = buf[p * 1088 + k];
        float2 zn = buf[p * 1088 + ((1024 - k) & 1023)];
        float2 val = which ? make_float2(0.5f * (zk.y + zn.y), 0.5f * (zn.x - zk.x))
                           : make_float2(0.5f * (zk.x + zn.x), 0.5f * (zk.y - zn.y));
        rf2[((long long)b * WR + k) * 1024 + h0 + j] = val;
    }
}

// ---------------------------------------------------------------------------
// Kernel B: 2 waves/block, each wave = one contiguous 8KB row FFT of rf2[b][k][:].
// ---------------------------------------------------------------------------
__global__ __launch_bounds__(128, 4) void col_fft_kernel(float2* __restrict__ rf2,
                                                         float* __restrict__ magmax) {
    __shared__ float2 buf[2 * 1088];
    const int t = threadIdx.x, w = t >> 6, lane = t & 63;
    const int fid = blockIdx.x * 2 + w;
    const int b = fid / WR, k = fid - b * WR;
    float2* row = rf2 + ((long long)b * WR + k) * 1024;
    float2 v[16];
#pragma unroll
    for (int j = 0; j < 16; ++j) v[j] = row[lane + 64 * j];
    wave_fft1024(v, buf + w * 1088, lane);
    float* pu = (float*)row;
    const int kq = 2 * ((lane >> 4) & 1) + ((lane >> 5) & 1);
    const int hbase = (lane & 15) + 256 * kq;
    float mmax = 0.0f;
#pragma unroll
    for (int m = 0; m < 16; ++m) {
        float2 z = v[m];
        mmax = fmaxf(mmax, sqrtf(z.x * z.x + z.y * z.y));
        float ph = atan2f(z.y, z.x);
        pu[hbase + 16 * m] = (ph < 0.0f) ? ph + TWO_PI_F : ph;
    }
#pragma unroll
    for (int off = 32; off; off >>= 1) mmax = fmaxf(mmax, __shfl_down(mmax, off));
    if (lane == 0) atomicMax((int*)(magmax + b), __float_as_int(mmax));
}

// ---------------------------------------------------------------------------
// Kernel C1: gradient stats + 30 cos-moments. All accumulators are NAMED
// scalars (no arrays, no runtime indices) so nothing can land in scratch.
// ---------------------------------------------------------------------------
#define WAVE_RED_ADD(var, dst)                                             \
    {                                                                      \
        float r_ = var;                                                    \
        _Pragma("unroll")                                                  \
        for (int off_ = 32; off_; off_ >>= 1) r_ += __shfl_down(r_, off_); \
        if (lane0) atomicAdd(dst, r_);                                     \
    }

__global__ __launch_bounds__(256, 2) void stats_cos_kernel(const float* __restrict__ pu,
                                                           float* __restrict__ acc) {
    const int b = blockIdx.y;
    const int k0 = blockIdx.x * 9;
    const float* base = pu + (long long)b * WR * 2048;
    float a00 = 0.f, a11 = 0.f, a20 = 0.f, a22 = 0.f, a31 = 0.f, a33 = 0.f,
          a40 = 0.f, a42 = 0.f, a44 = 0.f, a51 = 0.f, a53 = 0.f, a55 = 0.f,
          a60 = 0.f, a62 = 0.f, a64 = 0.f, a66 = 0.f, a71 = 0.f, a73 = 0.f,
          a75 = 0.f, a77 = 0.f, a80 = 0.f, a82 = 0.f, a84 = 0.f, a86 = 0.f,
          a88 = 0.f, a91 = 0.f, a93 = 0.f, a95 = 0.f, a97 = 0.f, a99 = 0.f;
    float sgx = 0.f, sgx2 = 0.f, sgy = 0.f, sgy2 = 0.f;

    for (int kk = 0; kk < 9; ++kk) {
        const int k = k0 + kk;
        const float* rowc = base + (long long)k * 2048;
        const float* rowm = rowc - 2048;
        const float* rowp = rowc + 2048;
        const float xv = -1.0f + (1.0f / 256.0f) * (float)k;
        const float xv2 = xv * xv;
        for (int h = threadIdx.x; h < 1024; h += 256) {
            float v = rowc[h];
            float gx, gy;
            if (k == 0)            gx = rowp[h] - v;
            else if (k == WR - 1)  gx = v - rowm[h];
            else                   gx = 0.5f * (rowp[h] - rowm[h]);
            if (h == 0)            gy = rowc[1] - v;
            else if (h == 1023)    gy = v - rowc[1022];
            else                   gy = 0.5f * (rowc[h + 1] - rowc[h - 1]);
            sgx += gx; sgx2 += gx * gx; sgy += gy; sgy2 += gy * gy;

            const float yv = -1.0f + (2.0f / 1023.0f) * (float)h;
            const float r2 = xv2 + yv * yv;
            if (r2 <= 1.0f) {
                const float rho = sqrtf(r2);
                const float inv = rsqrtf(r2);
                const float c1 = xv * inv;
                const float c2 = 2.f * c1 * c1 - 1.f;
                const float c3 = 2.f * c1 * c2 - c1;
                const float c4 = 2.f * c1 * c3 - c2;
                const float c5 = 2.f * c1 * c4 - c3;
                const float c6 = 2.f * c1 * c5 - c4;
                const float c7 = 2.f * c1 * c6 - c5;
                const float c8 = 2.f * c1 * c7 - c6;
                const float c9 = 2.f * c1 * c8 - c7;
                const float w0 = v,       w1 = w0 * rho, w2 = w1 * rho, w3 = w2 * rho,
                            w4 = w3 * rho, w5 = w4 * rho, w6 = w5 * rho, w7 = w6 * rho,
                            w8 = w7 * rho, w9 = w8 * rho;
                a00 += w0;
                a11 += w1 * c1;
                a20 += w2;      a22 += w2 * c2;
                a31 += w3 * c1; a33 += w3 * c3;
                a40 += w4;      a42 += w4 * c2; a44 += w4 * c4;
                a51 += w5 * c1; a53 += w5 * c3; a55 += w5 * c5;
                a60 += w6;      a62 += w6 * c2; a64 += w6 * c4; a66 += w6 * c6;
                a71 += w7 * c1; a73 += w7 * c3; a75 += w7 * c5; a77 += w7 * c7;
                a80 += w8;      a82 += w8 * c2; a84 += w8 * c4; a86 += w8 * c6; a88 += w8 * c8;
                a91 += w9 * c1; a93 += w9 * c3; a95 += w9 * c5; a97 += w9 * c7; a99 += w9 * c9;
            }
        }
    }

    float* ab = acc + b * 64;
    const bool lane0 = ((threadIdx.x & 63) == 0);
    WAVE_RED_ADD(a00, &ab[0]);  WAVE_RED_ADD(a11, &ab[1]);  WAVE_RED_ADD(a20, &ab[2]);
    WAVE_RED_ADD(a22, &ab[3]);  WAVE_RED_ADD(a31, &ab[4]);  WAVE_RED_ADD(a33, &ab[5]);
    WAVE_RED_ADD(a40, &ab[6]);  WAVE_RED_ADD(a42, &ab[7]);  WAVE_RED_ADD(a44, &ab[8]);
    WAVE_RED_ADD(a51, &ab[9]);  WAVE_RED_ADD(a53, &ab[10]); WAVE_RED_ADD(a55, &ab[11]);
    WAVE_RED_ADD(a60, &ab[12]); WAVE_RED_ADD(a62, &ab[13]); WAVE_RED_ADD(a64, &ab[14]);
    WAVE_RED_ADD(a66, &ab[15]); WAVE_RED_ADD(a71, &ab[16]); WAVE_RED_ADD(a73, &ab[17]);
    WAVE_RED_ADD(a75, &ab[18]); WAVE_RED_ADD(a77, &ab[19]); WAVE_RED_ADD(a80, &ab[20]);
    WAVE_RED_ADD(a82, &ab[21]); WAVE_RED_ADD(a84, &ab[22]); WAVE_RED_ADD(a86, &ab[23]);
    WAVE_RED_ADD(a88, &ab[24]); WAVE_RED_ADD(a91, &ab[25]); WAVE_RED_ADD(a93, &ab[26]);
    WAVE_RED_ADD(a95, &ab[27]); WAVE_RED_ADD(a97, &ab[28]); WAVE_RED_ADD(a99, &ab[29]);
    WAVE_RED_ADD(sgx, &ab[55]); WAVE_RED_ADD(sgx2, &ab[56]);
    WAVE_RED_ADD(sgy, &ab[57]); WAVE_RED_ADD(sgy2, &ab[58]);
}

// ---------------------------------------------------------------------------
// Kernel C2: 25 sin-moments + mask count. Named scalars only.
// ---------------------------------------------------------------------------
__global__ __launch_bounds__(256, 2) void stats_sin_kernel(const float* __restrict__ pu,
                                                           float* __restrict__ acc,
                                                           float* __restrict__ maskcnt) {
    const int b = blockIdx.y;
    const int k0 = blockIdx.x * 9;
    const float* base = pu + (long long)b * WR * 2048;
    float b11 = 0.f, b22 = 0.f, b31 = 0.f, b33 = 0.f, b42 = 0.f, b44 = 0.f,
          b51 = 0.f, b53 = 0.f, b55 = 0.f, b62 = 0.f, b64 = 0.f, b66 = 0.f,
          b71 = 0.f, b73 = 0.f, b75 = 0.f, b77 = 0.f, b82 = 0.f, b84 = 0.f,
          b86 = 0.f, b88 = 0.f, b91 = 0.f, b93 = 0.f, b95 = 0.f, b97 = 0.f,
          b99 = 0.f;
    float cnt = 0.f;

    for (int kk = 0; kk < 9; ++kk) {
        const int k = k0 + kk;
        const float* rowc = base + (long long)k * 2048;
        const float xv = -1.0f + (1.0f / 256.0f) * (float)k;
        const float xv2 = xv * xv;
        for (int h = threadIdx.x; h < 1024; h += 256) {
            float v = rowc[h];
            const float yv = -1.0f + (2.0f / 1023.0f) * (float)h;
            const float r2 = xv2 + yv * yv;
            if (r2 <= 1.0f) {
                cnt += 1.0f;
                const float rho = sqrtf(r2);
                const float inv = rsqrtf(r2);
                const float c1 = xv * inv;
                const float s1 = yv * inv;
                const float s2 = 2.f * c1 * s1;
                const float s3 = 2.f * c1 * s2 - s1;
                const float s4 = 2.f * c1 * s3 - s2;
                const float s5 = 2.f * c1 * s4 - s3;
                const float s6 = 2.f * c1 * s5 - s4;
                const float s7 = 2.f * c1 * s6 - s5;
                const float s8 = 2.f * c1 * s7 - s6;
                const float s9 = 2.f * c1 * s8 - s7;
                const float w1 = v * rho,  w2 = w1 * rho, w3 = w2 * rho,
                            w4 = w3 * rho, w5 = w4 * rho, w6 = w5 * rho,
                            w7 = w6 * rho, w8 = w7 * rho, w9 = w8 * rho;
                b11 += w1 * s1;
                b22 += w2 * s2;
                b31 += w3 * s1; b33 += w3 * s3;
                b42 += w4 * s2; b44 += w4 * s4;
                b51 += w5 * s1; b53 += w5 * s3; b55 += w5 * s5;
                b62 += w6 * s2; b64 += w6 * s4; b66 += w6 * s6;
                b71 += w7 * s1; b73 += w7 * s3; b75 += w7 * s5; b77 += w7 * s7;
                b82 += w8 * s2; b84 += w8 * s4; b86 += w8 * s6; b88 += w8 * s8;
                b91 += w9 * s1; b93 += w9 * s3; b95 += w9 * s5; b97 += w9 * s7; b99 += w9 * s9;
            }
        }
    }

    float* ab = acc + b * 64;
    const bool lane0 = ((threadIdx.x & 63) == 0);
    WAVE_RED_ADD(b11, &ab[30]); WAVE_RED_ADD(b22, &ab[31]); WAVE_RED_ADD(b31, &ab[32]);
    WAVE_RED_ADD(b33, &ab[33]); WAVE_RED_ADD(b42, &ab[34]); WAVE_RED_ADD(b44, &ab[35]);
    WAVE_RED_ADD(b51, &ab[36]); WAVE_RED_ADD(b53, &ab[37]); WAVE_RED_ADD(b55, &ab[38]);
    WAVE_RED_ADD(b62, &ab[39]); WAVE_RED_ADD(b64, &ab[40]); WAVE_RED_ADD(b66, &ab[41]);
    WAVE_RED_ADD(b71, &ab[42]); WAVE_RED_ADD(b73, &ab[43]); WAVE_RED_ADD(b75, &ab[44]);
    WAVE_RED_ADD(b77, &ab[45]); WAVE_RED_ADD(b82, &ab[46]); WAVE_RED_ADD(b84, &ab[47]);
    WAVE_RED_ADD(b86, &ab[48]); WAVE_RED_ADD(b88, &ab[49]); WAVE_RED_ADD(b91, &ab[50]);
    WAVE_RED_ADD(b93, &ab[51]); WAVE_RED_ADD(b95, &ab[52]); WAVE_RED_ADD(b97, &ab[53]);
    WAVE_RED_ADD(b99, &ab[54]);
    if (b == 0) WAVE_RED_ADD(cnt, maskcnt);
}

// ---------------------------------------------------------------------------
// Kernel D: map moments -> Zernike coefficients, finalize stats
// ---------------------------------------------------------------------------
__device__ int moment_index(int p, int a, int is_cos) {
    int ai = 0;
    for (int pp = 0; pp < 10; ++pp)
        for (int aa = (pp & 1); aa <= pp; aa += 2) {
            if (is_cos && pp == p && aa == a) return ai;
            ++ai;
        }
    for (int pp = 1; pp < 10; ++pp)
        for (int aa = ((pp & 1) ? 1 : 2); aa <= pp; aa += 2) {
            if (!is_cos && pp == p && aa == a) return ai;
            ++ai;
        }
    return 0;
}

__device__ float factf(int n) {
    float f = 1.0f;
    for (int i = 2; i <= n; ++i) f *= (float)i;
    return f;
}

__global__ void finalize_kernel(const float* __restrict__ acc,
                                const float* __restrict__ maskcnt,
                                const float* __restrict__ magmax,
                                float* __restrict__ out) {
    int b = blockIdx.x;
    int j = threadIdx.x;
    if (j >= 60) return;
    const float* ab = acc + b * 64;
    const float NF = (float)NPIX;
    float val;
    if (j < 55) {
        int tt = j, n = 0;
        while (tt >= n + 1) { tt -= (n + 1); ++n; }
        int m = -n + 2 * tt;
        int am = m < 0 ? -m : m;
        float s = 0.0f;
        for (int k = 0; k <= (n - am) / 2; ++k) {
            float c = factf(n - k) /
                      (factf(k) * factf((n + am) / 2 - k) * factf((n - am) / 2 - k));
            if (k & 1) c = -c;
            int p = n - 2 * k;
            s += c * ab[moment_index(p, am, m >= 0 ? 1 : 0)];
        }
        val = s / maskcnt[0];
    } else if (j == 55) {
        val = ab[55] / NF;
    } else if (j == 56) {
        val = ab[57] / NF;
    } else if (j == 57) {
        float sum = ab[55], sq = ab[56];
        val = sqrtf(fmaxf(0.0f, (sq - sum * sum / NF) / (NF - 1.0f)));
    } else if (j == 58) {
        float sum = ab[57], sq = ab[58];
        val = sqrtf(fmaxf(0.0f, (sq - sum * sum / NF) / (NF - 1.0f)));
    } else {
        val = magmax[b];
    }
    out[b * 60 + j] = val;
}

// ---------------------------------------------------------------------------
extern "C" void kernel_launch(void* const* d_in, const int* in_sizes, int n_in,
                              void* d_out, int out_size, void* d_ws, size_t ws_size,
                              hipStream_t stream) {
    (void)in_sizes; (void)n_in; (void)out_size; (void)ws_size;
    const float* x = (const float*)d_in[0];
    float* out = (float*)d_out;

    float* acc = (float*)d_ws;
    float* magmax = acc + 32 * 64;
    float* maskcnt = magmax + 32;
    float2* rf2 = (float2*)((char*)d_ws + 16384);  // [B][WR][H] float2 = 134.5 MB

    hipMemsetAsync(d_ws, 0, 16384, stream);
    row_fft_kernel<<<BATCH * 128, 256, 0, stream>>>(x, rf2);
    col_fft_kernel<<<(BATCH * WR) / 2, 128, 0, stream>>>(rf2, magmax);
    dim3 gridC(57, BATCH);
    stats_cos_kernel<<<gridC, 256, 0, stream>>>((const float*)rf2, acc);
    stats_sin_kernel<<<gridC, 256, 0, stream>>>((const float*)rf2, acc, maskcnt);
    finalize_kernel<<<BATCH, 64, 0, stream>>>(acc, maskcnt, magmax, out);
}

// Round 6
// 524.575 us; speedup vs baseline: 3.5449x; 1.3336x over previous
//
#include <hip/hip_runtime.h>
#include <math.h>

#define BATCH 32
#define HH 1024
#define WW 1024
#define WR 513
#define NPIX (HH * WR)
#define TWO_PI_F 6.28318530717958647692f

__device__ __forceinline__ float2 cadd(float2 a, float2 b) { return make_float2(a.x + b.x, a.y + b.y); }
__device__ __forceinline__ float2 csub(float2 a, float2 b) { return make_float2(a.x - b.x, a.y - b.y); }
__device__ __forceinline__ float2 cmul(float2 a, float2 b) {
    return make_float2(a.x * b.x - a.y * b.y, a.x * b.y + a.y * b.x);
}

// Natural-order 16-point FFT, in place, fully in registers (Stockham radix-4 x2).
__device__ __forceinline__ void fft16(float2* d) {
    float2 b[16];
#pragma unroll
    for (int t = 0; t < 4; ++t) {
        float2 x0 = d[t], x1 = d[t + 4], x2 = d[t + 8], x3 = d[t + 12];
        float2 a0 = cadd(x0, x2), a1 = csub(x0, x2), a2 = cadd(x1, x3), a3 = csub(x1, x3);
        b[4 * t + 0] = cadd(a0, a2);
        b[4 * t + 1] = make_float2(a1.x + a3.y, a1.y - a3.x);
        b[4 * t + 2] = csub(a0, a2);
        b[4 * t + 3] = make_float2(a1.x - a3.y, a1.y + a3.x);
    }
    const float2 W1[4] = {make_float2(1.0f, 0.0f),
                          make_float2(0.92387953f, -0.38268343f),
                          make_float2(0.70710678f, -0.70710678f),
                          make_float2(0.38268343f, -0.92387953f)};
#pragma unroll
    for (int t = 0; t < 4; ++t) {
        float2 w1 = W1[t], w2 = cmul(w1, w1), w3 = cmul(w2, w1);
        float2 x0 = b[t], x1 = cmul(b[t + 4], w1), x2 = cmul(b[t + 8], w2), x3 = cmul(b[t + 12], w3);
        float2 a0 = cadd(x0, x2), a1 = csub(x0, x2), a2 = cadd(x1, x3), a3 = csub(x1, x3);
        d[t + 0]  = cadd(a0, a2);
        d[t + 4]  = make_float2(a1.x + a3.y, a1.y - a3.x);
        d[t + 8]  = csub(a0, a2);
        d[t + 12] = make_float2(a1.x - a3.y, a1.y + a3.x);
    }
}

// Wave-level 1024-pt FFT. Input: v[j] = x[lane + 64*j]. buf = this wave's 1088-float2 LDS.
// Output: v[m] = X[(lane&15) + 16*m + 256*kq], kq = 2*((lane>>4)&1) + ((lane>>5)&1).
__device__ __forceinline__ void wave_fft1024(float2* v, float2* buf, int lane) {
    fft16(v);
    float s, c;
    __sincosf(-TWO_PI_F * (float)lane * (1.0f / 1024.0f), &s, &c);
    float2 T = make_float2(c, s), w = T;
#pragma unroll
    for (int k2 = 1; k2 < 16; ++k2) { v[k2] = cmul(v[k2], w); w = cmul(w, T); }
#pragma unroll
    for (int k2 = 0; k2 < 16; ++k2) buf[68 * k2 + lane] = v[k2];
    __syncthreads();
    const int k2p = lane & 15, qp = lane >> 4;
#pragma unroll
    for (int m = 0; m < 16; ++m) v[m] = buf[68 * k2p + 4 * m + qp];
    __syncthreads();
    fft16(v);
    __sincosf(-TWO_PI_F * (float)qp * (1.0f / 64.0f), &s, &c);
    float2 U = make_float2(c, s);
    w = U;
#pragma unroll
    for (int km = 1; km < 16; ++km) { v[km] = cmul(v[km], w); w = cmul(w, U); }
    const bool hi2 = (lane & 32) != 0, hi1 = (lane & 16) != 0;
#pragma unroll
    for (int m = 0; m < 16; ++m) {
        float2 a = v[m];
        float2 o = make_float2(__shfl_xor(a.x, 32, 64), __shfl_xor(a.y, 32, 64));
        float2 s1 = hi2 ? csub(o, a) : cadd(a, o);
        if (hi2 && hi1) s1 = make_float2(s1.y, -s1.x);
        float2 o2 = make_float2(__shfl_xor(s1.x, 16, 64), __shfl_xor(s1.y, 16, 64));
        v[m] = hi1 ? csub(o2, s1) : cadd(s1, o2);
    }
}

// ---------------------------------------------------------------------------
// Kernel A: 4 waves/block, each wave = 2 packed real rows -> 1 complex FFT.
// ---------------------------------------------------------------------------
__global__ __launch_bounds__(256, 4) void row_fft_kernel(const float* __restrict__ x,
                                                         float2* __restrict__ rf2) {
    __shared__ float2 buf[4 * 1088];
    const int t = threadIdx.x, w = t >> 6, lane = t & 63;
    const int b = blockIdx.x >> 7;
    const int h0 = (blockIdx.x & 127) * 8;
    const float* r0 = x + ((long long)b * HH + h0 + 2 * w) * (long long)WW;
    const float* r1 = r0 + WW;
    float2 v[16];
#pragma unroll
    for (int j = 0; j < 16; ++j) v[j] = make_float2(r0[lane + 64 * j], r1[lane + 64 * j]);
    float2* mybuf = buf + w * 1088;
    wave_fft1024(v, mybuf, lane);
    const int kq = 2 * ((lane >> 4) & 1) + ((lane >> 5) & 1);
    const int kbase = (lane & 15) + 256 * kq;
#pragma unroll
    for (int m = 0; m < 16; ++m) mybuf[kbase + 16 * m] = v[m];
    __syncthreads();
    for (int idx = t; idx < 513 * 8; idx += 256) {
        int k = idx >> 3, j = idx & 7, p = j >> 1, which = j & 1;
        float2 zk = buf[p * 1088 + k];
        float2 zn = buf[p * 1088 + ((1024 - k) & 1023)];
        float2 val = which ? make_float2(0.5f * (zk.y + zn.y), 0.5f * (zn.x - zk.x))
                           : make_float2(0.5f * (zk.x + zn.x), 0.5f * (zk.y - zn.y));
        rf2[((long long)b * WR + k) * 1024 + h0 + j] = val;
    }
}

// ---------------------------------------------------------------------------
// Kernel B: 2 waves/block, each wave = one contiguous 8KB row FFT of rf2[b][k][:].
// Phase written compactly into floats 0..1023 of the row; floats 1024..2047
// become dead space (reused as partial-sum scratch by stats_kernel).
// ---------------------------------------------------------------------------
__global__ __launch_bounds__(128, 4) void col_fft_kernel(float2* __restrict__ rf2,
                                                         float* __restrict__ magmax) {
    __shared__ float2 buf[2 * 1088];
    const int t = threadIdx.x, w = t >> 6, lane = t & 63;
    const int fid = blockIdx.x * 2 + w;
    const int b = fid / WR, k = fid - b * WR;
    float2* row = rf2 + ((long long)b * WR + k) * 1024;
    float2 v[16];
#pragma unroll
    for (int j = 0; j < 16; ++j) v[j] = row[lane + 64 * j];
    wave_fft1024(v, buf + w * 1088, lane);
    float* pu = (float*)row;
    const int kq = 2 * ((lane >> 4) & 1) + ((lane >> 5) & 1);
    const int hbase = (lane & 15) + 256 * kq;
    float mmax = 0.0f;
#pragma unroll
    for (int m = 0; m < 16; ++m) {
        float2 z = v[m];
        mmax = fmaxf(mmax, sqrtf(z.x * z.x + z.y * z.y));
        float ph = atan2f(z.y, z.x);
        pu[hbase + 16 * m] = (ph < 0.0f) ? ph + TWO_PI_F : ph;
    }
#pragma unroll
    for (int off = 32; off; off >>= 1) mmax = fmaxf(mmax, __shfl_down(mmax, off));
    if (lane == 0) atomicMax((int*)(magmax + b), __float_as_int(mmax));
}

// ---------------------------------------------------------------------------
// Kernel C: single-pass gradients + all 55 Zernike moments + mask count.
// NO atomics: wave shuffle-reduce -> LDS -> per-block partial (60 floats)
// stored with plain coalesced writes into the dead upper half of pu row
// (b*57 + blockIdx.x), floats 1024..1083 of that 2048-float row.
// ---------------------------------------------------------------------------
#define WRED(var, idx)                                                     \
    {                                                                      \
        float r_ = var;                                                    \
        _Pragma("unroll")                                                  \
        for (int off_ = 32; off_; off_ >>= 1) r_ += __shfl_down(r_, off_); \
        if (lane == 0) red[wv * 64 + (idx)] = r_;                          \
    }

__global__ __launch_bounds__(256, 2) void stats_kernel(float* __restrict__ pu) {
    __shared__ float red[4 * 64];
    const int b = blockIdx.y;
    const int k0 = blockIdx.x * 9;
    const float* base = pu + (long long)b * WR * 2048;
    float a00 = 0.f, a11 = 0.f, a20 = 0.f, a22 = 0.f, a31 = 0.f, a33 = 0.f,
          a40 = 0.f, a42 = 0.f, a44 = 0.f, a51 = 0.f, a53 = 0.f, a55 = 0.f,
          a60 = 0.f, a62 = 0.f, a64 = 0.f, a66 = 0.f, a71 = 0.f, a73 = 0.f,
          a75 = 0.f, a77 = 0.f, a80 = 0.f, a82 = 0.f, a84 = 0.f, a86 = 0.f,
          a88 = 0.f, a91 = 0.f, a93 = 0.f, a95 = 0.f, a97 = 0.f, a99 = 0.f;
    float b11 = 0.f, b22 = 0.f, b31 = 0.f, b33 = 0.f, b42 = 0.f, b44 = 0.f,
          b51 = 0.f, b53 = 0.f, b55 = 0.f, b62 = 0.f, b64 = 0.f, b66 = 0.f,
          b71 = 0.f, b73 = 0.f, b75 = 0.f, b77 = 0.f, b82 = 0.f, b84 = 0.f,
          b86 = 0.f, b88 = 0.f, b91 = 0.f, b93 = 0.f, b95 = 0.f, b97 = 0.f,
          b99 = 0.f;
    float sgx = 0.f, sgx2 = 0.f, sgy = 0.f, sgy2 = 0.f, cnt = 0.f;

    for (int kk = 0; kk < 9; ++kk) {
        const int k = k0 + kk;
        const float* rowc = base + (long long)k * 2048;
        const float* rowm = rowc - 2048;
        const float* rowp = rowc + 2048;
        const float xv = -1.0f + (1.0f / 256.0f) * (float)k;
        const float xv2 = xv * xv;
        for (int h = threadIdx.x; h < 1024; h += 256) {
            float v = rowc[h];
            float gx, gy;
            if (k == 0)            gx = rowp[h] - v;
            else if (k == WR - 1)  gx = v - rowm[h];
            else                   gx = 0.5f * (rowp[h] - rowm[h]);
            if (h == 0)            gy = rowc[1] - v;
            else if (h == 1023)    gy = v - rowc[1022];
            else                   gy = 0.5f * (rowc[h + 1] - rowc[h - 1]);
            sgx += gx; sgx2 += gx * gx; sgy += gy; sgy2 += gy * gy;

            const float yv = -1.0f + (2.0f / 1023.0f) * (float)h;
            const float r2 = xv2 + yv * yv;
            if (r2 <= 1.0f) {
                cnt += 1.0f;
                const float rho = sqrtf(r2);
                const float inv = rsqrtf(r2);
                const float c1 = xv * inv;
                const float s1 = yv * inv;
                const float c2 = 2.f * c1 * c1 - 1.f;
                const float c3 = 2.f * c1 * c2 - c1;
                const float c4 = 2.f * c1 * c3 - c2;
                const float c5 = 2.f * c1 * c4 - c3;
                const float c6 = 2.f * c1 * c5 - c4;
                const float c7 = 2.f * c1 * c6 - c5;
                const float c8 = 2.f * c1 * c7 - c6;
                const float c9 = 2.f * c1 * c8 - c7;
                const float s2 = 2.f * c1 * s1;
                const float s3 = 2.f * c1 * s2 - s1;
                const float s4 = 2.f * c1 * s3 - s2;
                const float s5 = 2.f * c1 * s4 - s3;
                const float s6 = 2.f * c1 * s5 - s4;
                const float s7 = 2.f * c1 * s6 - s5;
                const float s8 = 2.f * c1 * s7 - s6;
                const float s9 = 2.f * c1 * s8 - s7;
                const float w0 = v,        w1 = w0 * rho, w2 = w1 * rho, w3 = w2 * rho,
                            w4 = w3 * rho, w5 = w4 * rho, w6 = w5 * rho, w7 = w6 * rho,
                            w8 = w7 * rho, w9 = w8 * rho;
                a00 += w0;
                a11 += w1 * c1;
                a20 += w2;      a22 += w2 * c2;
                a31 += w3 * c1; a33 += w3 * c3;
                a40 += w4;      a42 += w4 * c2; a44 += w4 * c4;
                a51 += w5 * c1; a53 += w5 * c3; a55 += w5 * c5;
                a60 += w6;      a62 += w6 * c2; a64 += w6 * c4; a66 += w6 * c6;
                a71 += w7 * c1; a73 += w7 * c3; a75 += w7 * c5; a77 += w7 * c7;
                a80 += w8;      a82 += w8 * c2; a84 += w8 * c4; a86 += w8 * c6; a88 += w8 * c8;
                a91 += w9 * c1; a93 += w9 * c3; a95 += w9 * c5; a97 += w9 * c7; a99 += w9 * c9;
                b11 += w1 * s1;
                b22 += w2 * s2;
                b31 += w3 * s1; b33 += w3 * s3;
                b42 += w4 * s2; b44 += w4 * s4;
                b51 += w5 * s1; b53 += w5 * s3; b55 += w5 * s5;
                b62 += w6 * s2; b64 += w6 * s4; b66 += w6 * s6;
                b71 += w7 * s1; b73 += w7 * s3; b75 += w7 * s5; b77 += w7 * s7;
                b82 += w8 * s2; b84 += w8 * s4; b86 += w8 * s6; b88 += w8 * s8;
                b91 += w9 * s1; b93 += w9 * s3; b95 += w9 * s5; b97 += w9 * s7; b99 += w9 * s9;
            }
        }
    }

    const int wv = threadIdx.x >> 6, lane = threadIdx.x & 63;
    WRED(a00, 0);  WRED(a11, 1);  WRED(a20, 2);  WRED(a22, 3);  WRED(a31, 4);
    WRED(a33, 5);  WRED(a40, 6);  WRED(a42, 7);  WRED(a44, 8);  WRED(a51, 9);
    WRED(a53, 10); WRED(a55, 11); WRED(a60, 12); WRED(a62, 13); WRED(a64, 14);
    WRED(a66, 15); WRED(a71, 16); WRED(a73, 17); WRED(a75, 18); WRED(a77, 19);
    WRED(a80, 20); WRED(a82, 21); WRED(a84, 22); WRED(a86, 23); WRED(a88, 24);
    WRED(a91, 25); WRED(a93, 26); WRED(a95, 27); WRED(a97, 28); WRED(a99, 29);
    WRED(b11, 30); WRED(b22, 31); WRED(b31, 32); WRED(b33, 33); WRED(b42, 34);
    WRED(b44, 35); WRED(b51, 36); WRED(b53, 37); WRED(b55, 38); WRED(b62, 39);
    WRED(b64, 40); WRED(b66, 41); WRED(b71, 42); WRED(b73, 43); WRED(b75, 44);
    WRED(b77, 45); WRED(b82, 46); WRED(b84, 47); WRED(b86, 48); WRED(b88, 49);
    WRED(b91, 50); WRED(b93, 51); WRED(b95, 52); WRED(b97, 53); WRED(b99, 54);
    WRED(sgx, 55); WRED(sgx2, 56); WRED(sgy, 57); WRED(sgy2, 58); WRED(cnt, 59);
    __syncthreads();
    const int t = threadIdx.x;
    if (t < 60) {
        float s = red[t] + red[64 + t] + red[128 + t] + red[192 + t];
        // partial slot: dead upper half of pu row (b*57 + blockIdx.x)
        pu[((long long)(b * 57 + blockIdx.x)) * 2048 + 1024 + t] = s;
    }
}

// ---------------------------------------------------------------------------
// Kernel D: sum 57 block-partials per batch, map moments -> Zernike coeffs,
// finalize stats. One block per batch, 64 threads.
// ---------------------------------------------------------------------------
__device__ int moment_index(int p, int a, int is_cos) {
    int ai = 0;
    for (int pp = 0; pp < 10; ++pp)
        for (int aa = (pp & 1); aa <= pp; aa += 2) {
            if (is_cos && pp == p && aa == a) return ai;
            ++ai;
        }
    for (int pp = 1; pp < 10; ++pp)
        for (int aa = ((pp & 1) ? 1 : 2); aa <= pp; aa += 2) {
            if (!is_cos && pp == p && aa == a) return ai;
            ++ai;
        }
    return 0;
}

__device__ float factf(int n) {
    float f = 1.0f;
    for (int i = 2; i <= n; ++i) f *= (float)i;
    return f;
}

__global__ void finalize_kernel(const float* __restrict__ pu,
                                const float* __restrict__ magmax,
                                float* __restrict__ out) {
    __shared__ float abf[64];
    const int b = blockIdx.x;
    const int j = threadIdx.x;
    if (j < 60) {
        float s = 0.0f;
        for (int i = 0; i < 57; ++i)
            s += pu[((long long)(b * 57 + i)) * 2048 + 1024 + j];
        abf[j] = s;
    }
    __syncthreads();
    if (j >= 60) return;
    const float NF = (float)NPIX;
    float val;
    if (j < 55) {
        int tt = j, n = 0;
        while (tt >= n + 1) { tt -= (n + 1); ++n; }
        int m = -n + 2 * tt;
        int am = m < 0 ? -m : m;
        float s = 0.0f;
        for (int k = 0; k <= (n - am) / 2; ++k) {
            float c = factf(n - k) /
                      (factf(k) * factf((n + am) / 2 - k) * factf((n - am) / 2 - k));
            if (k & 1) c = -c;
            int p = n - 2 * k;
            s += c * abf[moment_index(p, am, m >= 0 ? 1 : 0)];
        }
        val = s / abf[59];
    } else if (j == 55) {
        val = abf[55] / NF;
    } else if (j == 56) {
        val = abf[57] / NF;
    } else if (j == 57) {
        float sum = abf[55], sq = abf[56];
        val = sqrtf(fmaxf(0.0f, (sq - sum * sum / NF) / (NF - 1.0f)));
    } else if (j == 58) {
        float sum = abf[57], sq = abf[58];
        val = sqrtf(fmaxf(0.0f, (sq - sum * sum / NF) / (NF - 1.0f)));
    } else {
        val = magmax[b];
    }
    out[b * 60 + j] = val;
}

// ---------------------------------------------------------------------------
extern "C" void kernel_launch(void* const* d_in, const int* in_sizes, int n_in,
                              void* d_out, int out_size, void* d_ws, size_t ws_size,
                              hipStream_t stream) {
    (void)in_sizes; (void)n_in; (void)out_size; (void)ws_size;
    const float* x = (const float*)d_in[0];
    float* out = (float*)d_out;

    float* magmax = (float*)d_ws;                  // 32 floats (atomicMax target)
    float2* rf2 = (float2*)((char*)d_ws + 16384);  // [B][WR][H] float2 = 134.5 MB

    hipMemsetAsync(d_ws, 0, 16384, stream);
    row_fft_kernel<<<BATCH * 128, 256, 0, stream>>>(x, rf2);
    col_fft_kernel<<<(BATCH * WR) / 2, 128, 0, stream>>>(rf2, magmax);
    dim3 gridC(57, BATCH);
    stats_kernel<<<gridC, 256, 0, stream>>>((float*)rf2);
    finalize_kernel<<<BATCH, 64, 0, stream>>>((const float*)rf2, magmax, out);
}

// Round 7
// 509.103 us; speedup vs baseline: 3.6526x; 1.0304x over previous
//
#include <hip/hip_runtime.h>
#include <math.h>

#define BATCH 32
#define HH 1024
#define WW 1024
#define WR 513
#define NPIX (HH * WR)
#define TWO_PI_F 6.28318530717958647692f

// Same-wave LDS fence: each wave only touches its own LDS region, so a full
// block barrier is unnecessary — wait for this wave's own LDS ops instead.
#define LGKM_SYNC() __asm__ __volatile__("s_waitcnt lgkmcnt(0)" ::: "memory")

__device__ __forceinline__ float2 cadd(float2 a, float2 b) { return make_float2(a.x + b.x, a.y + b.y); }
__device__ __forceinline__ float2 csub(float2 a, float2 b) { return make_float2(a.x - b.x, a.y - b.y); }
__device__ __forceinline__ float2 cmul(float2 a, float2 b) {
    return make_float2(a.x * b.x - a.y * b.y, a.x * b.y + a.y * b.x);
}

// atan2 via odd minimax poly on [0,1] (max err ~1e-5 rad) + quadrant fixup.
__device__ __forceinline__ float fast_atan2f(float y, float x) {
    float ax = __builtin_fabsf(x), ay = __builtin_fabsf(y);
    float mx = fmaxf(ax, ay), mn = fminf(ax, ay);
    float a = mn * __builtin_amdgcn_rcpf(mx);
    float s = a * a;
    float r = fmaf(fmaf(fmaf(fmaf(0.0208351f, s, -0.085133f), s, 0.180141f),
                        s, -0.3302995f), s, 0.999866f) * a;
    if (ay > ax) r = 1.5707963268f - r;
    if (x < 0.0f) r = 3.1415926536f - r;
    return (y < 0.0f) ? -r : r;
}

// Natural-order 16-point FFT, in place, fully in registers (Stockham radix-4 x2).
__device__ __forceinline__ void fft16(float2* d) {
    float2 b[16];
#pragma unroll
    for (int t = 0; t < 4; ++t) {
        float2 x0 = d[t], x1 = d[t + 4], x2 = d[t + 8], x3 = d[t + 12];
        float2 a0 = cadd(x0, x2), a1 = csub(x0, x2), a2 = cadd(x1, x3), a3 = csub(x1, x3);
        b[4 * t + 0] = cadd(a0, a2);
        b[4 * t + 1] = make_float2(a1.x + a3.y, a1.y - a3.x);
        b[4 * t + 2] = csub(a0, a2);
        b[4 * t + 3] = make_float2(a1.x - a3.y, a1.y + a3.x);
    }
    const float2 W1[4] = {make_float2(1.0f, 0.0f),
                          make_float2(0.92387953f, -0.38268343f),
                          make_float2(0.70710678f, -0.70710678f),
                          make_float2(0.38268343f, -0.92387953f)};
#pragma unroll
    for (int t = 0; t < 4; ++t) {
        float2 w1 = W1[t], w2 = cmul(w1, w1), w3 = cmul(w2, w1);
        float2 x0 = b[t], x1 = cmul(b[t + 4], w1), x2 = cmul(b[t + 8], w2), x3 = cmul(b[t + 12], w3);
        float2 a0 = cadd(x0, x2), a1 = csub(x0, x2), a2 = cadd(x1, x3), a3 = csub(x1, x3);
        d[t + 0]  = cadd(a0, a2);
        d[t + 4]  = make_float2(a1.x + a3.y, a1.y - a3.x);
        d[t + 8]  = csub(a0, a2);
        d[t + 12] = make_float2(a1.x - a3.y, a1.y + a3.x);
    }
}

// Wave-level 1024-pt FFT. Input: v[j] = x[lane + 64*j]. sb = this wave's
// PRIVATE 1088-float LDS scratch. No block barriers — lgkmcnt fences only.
// Output: v[m] = X[(lane&15) + 16*m + 256*kq], kq = 2*((lane>>4)&1) + ((lane>>5)&1).
__device__ __forceinline__ void wave_fft1024(float2* v, float* sb, int lane) {
    fft16(v);
    float s, c;
    __sincosf(-TWO_PI_F * (float)lane * (1.0f / 1024.0f), &s, &c);
    float2 T = make_float2(c, s), w = T;
#pragma unroll
    for (int k2 = 1; k2 < 16; ++k2) { v[k2] = cmul(v[k2], w); w = cmul(w, T); }
    // 16x64 transpose, two b32 passes at stride 68 (bank-conflict-free)
    const int k2p = lane & 15, qp = lane >> 4;
    float tx[16];
#pragma unroll
    for (int k2 = 0; k2 < 16; ++k2) sb[68 * k2 + lane] = v[k2].x;
    LGKM_SYNC();
#pragma unroll
    for (int m = 0; m < 16; ++m) tx[m] = sb[68 * k2p + 4 * m + qp];
    LGKM_SYNC();
#pragma unroll
    for (int k2 = 0; k2 < 16; ++k2) sb[68 * k2 + lane] = v[k2].y;
    LGKM_SYNC();
#pragma unroll
    for (int m = 0; m < 16; ++m) v[m] = make_float2(tx[m], sb[68 * k2p + 4 * m + qp]);
    LGKM_SYNC();                       // scratch reusable by caller after return
    fft16(v);
    __sincosf(-TWO_PI_F * (float)qp * (1.0f / 64.0f), &s, &c);
    float2 U = make_float2(c, s);
    w = U;
#pragma unroll
    for (int km = 1; km < 16; ++km) { v[km] = cmul(v[km], w); w = cmul(w, U); }
    const bool hi2 = (lane & 32) != 0, hi1 = (lane & 16) != 0;
#pragma unroll
    for (int m = 0; m < 16; ++m) {
        float2 a = v[m];
        float2 o = make_float2(__shfl_xor(a.x, 32, 64), __shfl_xor(a.y, 32, 64));
        float2 s1 = hi2 ? csub(o, a) : cadd(a, o);
        if (hi2 && hi1) s1 = make_float2(s1.y, -s1.x);
        float2 o2 = make_float2(__shfl_xor(s1.x, 16, 64), __shfl_xor(s1.y, 16, 64));
        v[m] = hi1 ? csub(o2, s1) : cadd(s1, o2);
    }
}

// ---------------------------------------------------------------------------
// Kernel A: 4 waves/block, each wave = 2 packed real rows -> 1 complex FFT.
// One block barrier total (before the cross-wave transposed flush).
// ---------------------------------------------------------------------------
__global__ __launch_bounds__(256, 4) void row_fft_kernel(const float* __restrict__ x,
                                                         float2* __restrict__ rf2) {
    __shared__ float2 buf[4 * 1088];
    const int t = threadIdx.x, w = t >> 6, lane = t & 63;
    const int b = blockIdx.x >> 7;
    const int h0 = (blockIdx.x & 127) * 8;
    const float* r0 = x + ((long long)b * HH + h0 + 2 * w) * (long long)WW;
    const float* r1 = r0 + WW;
    float2 v[16];
#pragma unroll
    for (int j = 0; j < 16; ++j) v[j] = make_float2(r0[lane + 64 * j], r1[lane + 64 * j]);
    float2* mybuf = buf + w * 1088;
    wave_fft1024(v, (float*)mybuf, lane);
    const int kq = 2 * ((lane >> 4) & 1) + ((lane >> 5) & 1);
    const int kbase = (lane & 15) + 256 * kq;
#pragma unroll
    for (int m = 0; m < 16; ++m) mybuf[kbase + 16 * m] = v[m];
    __syncthreads();
    for (int idx = t; idx < 513 * 8; idx += 256) {
        int k = idx >> 3, j = idx & 7, p = j >> 1, which = j & 1;
        float2 zk = buf[p * 1088 + k];
        float2 zn = buf[p * 1088 + ((1024 - k) & 1023)];
        float2 val = which ? make_float2(0.5f * (zk.y + zn.y), 0.5f * (zn.x - zk.x))
                           : make_float2(0.5f * (zk.x + zn.x), 0.5f * (zk.y - zn.y));
        rf2[((long long)b * WR + k) * 1024 + h0 + j] = val;
    }
}

// ---------------------------------------------------------------------------
// Kernel B: 2 waves/block, each wave = one contiguous 8KB row FFT of rf2[b][k][:].
// Barrier-free; 8.7 KB LDS/block. Phase into floats 0..1023 of the row
// (floats 1024..2047 = dead space reused by stats partials).
// ---------------------------------------------------------------------------
__global__ __launch_bounds__(128, 4) void col_fft_kernel(float2* __restrict__ rf2,
                                                         float* __restrict__ magmax) {
    __shared__ float sb[2 * 1088];
    const int t = threadIdx.x, w = t >> 6, lane = t & 63;
    const int fid = blockIdx.x * 2 + w;
    const int b = fid / WR, k = fid - b * WR;
    float2* row = rf2 + ((long long)b * WR + k) * 1024;
    float2 v[16];
#pragma unroll
    for (int j = 0; j < 16; ++j) v[j] = row[lane + 64 * j];
    wave_fft1024(v, sb + w * 1088, lane);
    float* pu = (float*)row;
    const int kq = 2 * ((lane >> 4) & 1) + ((lane >> 5) & 1);
    const int hbase = (lane & 15) + 256 * kq;
    float mmax = 0.0f;
#pragma unroll
    for (int m = 0; m < 16; ++m) {
        float2 z = v[m];
        mmax = fmaxf(mmax, __builtin_amdgcn_sqrtf(z.x * z.x + z.y * z.y));
        float ph = fast_atan2f(z.y, z.x);
        pu[hbase + 16 * m] = (ph < 0.0f) ? ph + TWO_PI_F : ph;
    }
#pragma unroll
    for (int off = 32; off; off >>= 1) mmax = fmaxf(mmax, __shfl_down(mmax, off));
    if (lane == 0) atomicMax((int*)(magmax + b), __float_as_int(mmax));
}

// ---------------------------------------------------------------------------
// Kernel C: single-pass gradients + all 55 Zernike moments + mask count.
// No atomics: wave shuffle-reduce -> LDS -> per-block 60-float partial into
// the dead upper half of pu row (b*57 + blockIdx.x).
// ---------------------------------------------------------------------------
#define WRED(var, idx)                                                     \
    {                                                                      \
        float r_ = var;                                                    \
        _Pragma("unroll")                                                  \
        for (int off_ = 32; off_; off_ >>= 1) r_ += __shfl_down(r_, off_); \
        if (lane == 0) red[wv * 64 + (idx)] = r_;                          \
    }

__global__ __launch_bounds__(256, 2) void stats_kernel(float* __restrict__ pu) {
    __shared__ float red[4 * 64];
    const int b = blockIdx.y;
    const int k0 = blockIdx.x * 9;
    const float* base = pu + (long long)b * WR * 2048;
    float a00 = 0.f, a11 = 0.f, a20 = 0.f, a22 = 0.f, a31 = 0.f, a33 = 0.f,
          a40 = 0.f, a42 = 0.f, a44 = 0.f, a51 = 0.f, a53 = 0.f, a55 = 0.f,
          a60 = 0.f, a62 = 0.f, a64 = 0.f, a66 = 0.f, a71 = 0.f, a73 = 0.f,
          a75 = 0.f, a77 = 0.f, a80 = 0.f, a82 = 0.f, a84 = 0.f, a86 = 0.f,
          a88 = 0.f, a91 = 0.f, a93 = 0.f, a95 = 0.f, a97 = 0.f, a99 = 0.f;
    float b11 = 0.f, b22 = 0.f, b31 = 0.f, b33 = 0.f, b42 = 0.f, b44 = 0.f,
          b51 = 0.f, b53 = 0.f, b55 = 0.f, b62 = 0.f, b64 = 0.f, b66 = 0.f,
          b71 = 0.f, b73 = 0.f, b75 = 0.f, b77 = 0.f, b82 = 0.f, b84 = 0.f,
          b86 = 0.f, b88 = 0.f, b91 = 0.f, b93 = 0.f, b95 = 0.f, b97 = 0.f,
          b99 = 0.f;
    float sgx = 0.f, sgx2 = 0.f, sgy = 0.f, sgy2 = 0.f, cnt = 0.f;

    for (int kk = 0; kk < 9; ++kk) {
        const int k = k0 + kk;
        const float* rowc = base + (long long)k * 2048;
        const float* rowm = rowc - 2048;
        const float* rowp = rowc + 2048;
        const float xv = -1.0f + (1.0f / 256.0f) * (float)k;
        const float xv2 = xv * xv;
        for (int h = threadIdx.x; h < 1024; h += 256) {
            float v = rowc[h];
            float gx, gy;
            if (k == 0)            gx = rowp[h] - v;
            else if (k == WR - 1)  gx = v - rowm[h];
            else                   gx = 0.5f * (rowp[h] - rowm[h]);
            if (h == 0)            gy = rowc[1] - v;
            else if (h == 1023)    gy = v - rowc[1022];
            else                   gy = 0.5f * (rowc[h + 1] - rowc[h - 1]);
            sgx += gx; sgx2 += gx * gx; sgy += gy; sgy2 += gy * gy;

            const float yv = -1.0f + (2.0f / 1023.0f) * (float)h;
            const float r2 = xv2 + yv * yv;
            if (r2 <= 1.0f) {
                cnt += 1.0f;
                const float rho = sqrtf(r2);
                const float inv = rsqrtf(r2);
                const float c1 = xv * inv;
                const float s1 = yv * inv;
                const float c2 = 2.f * c1 * c1 - 1.f;
                const float c3 = 2.f * c1 * c2 - c1;
                const float c4 = 2.f * c1 * c3 - c2;
                const float c5 = 2.f * c1 * c4 - c3;
                const float c6 = 2.f * c1 * c5 - c4;
                const float c7 = 2.f * c1 * c6 - c5;
                const float c8 = 2.f * c1 * c7 - c6;
                const float c9 = 2.f * c1 * c8 - c7;
                const float s2 = 2.f * c1 * s1;
                const float s3 = 2.f * c1 * s2 - s1;
                const float s4 = 2.f * c1 * s3 - s2;
                const float s5 = 2.f * c1 * s4 - s3;
                const float s6 = 2.f * c1 * s5 - s4;
                const float s7 = 2.f * c1 * s6 - s5;
                const float s8 = 2.f * c1 * s7 - s6;
                const float s9 = 2.f * c1 * s8 - s7;
                const float w0 = v,        w1 = w0 * rho, w2 = w1 * rho, w3 = w2 * rho,
                            w4 = w3 * rho, w5 = w4 * rho, w6 = w5 * rho, w7 = w6 * rho,
                            w8 = w7 * rho, w9 = w8 * rho;
                a00 += w0;
                a11 += w1 * c1;
                a20 += w2;      a22 += w2 * c2;
                a31 += w3 * c1; a33 += w3 * c3;
                a40 += w4;      a42 += w4 * c2; a44 += w4 * c4;
                a51 += w5 * c1; a53 += w5 * c3; a55 += w5 * c5;
                a60 += w6;      a62 += w6 * c2; a64 += w6 * c4; a66 += w6 * c6;
                a71 += w7 * c1; a73 += w7 * c3; a75 += w7 * c5; a77 += w7 * c7;
                a80 += w8;      a82 += w8 * c2; a84 += w8 * c4; a86 += w8 * c6; a88 += w8 * c8;
                a91 += w9 * c1; a93 += w9 * c3; a95 += w9 * c5; a97 += w9 * c7; a99 += w9 * c9;
                b11 += w1 * s1;
                b22 += w2 * s2;
                b31 += w3 * s1; b33 += w3 * s3;
                b42 += w4 * s2; b44 += w4 * s4;
                b51 += w5 * s1; b53 += w5 * s3; b55 += w5 * s5;
                b62 += w6 * s2; b64 += w6 * s4; b66 += w6 * s6;
                b71 += w7 * s1; b73 += w7 * s3; b75 += w7 * s5; b77 += w7 * s7;
                b82 += w8 * s2; b84 += w8 * s4; b86 += w8 * s6; b88 += w8 * s8;
                b91 += w9 * s1; b93 += w9 * s3; b95 += w9 * s5; b97 += w9 * s7; b99 += w9 * s9;
            }
        }
    }

    const int wv = threadIdx.x >> 6, lane = threadIdx.x & 63;
    WRED(a00, 0);  WRED(a11, 1);  WRED(a20, 2);  WRED(a22, 3);  WRED(a31, 4);
    WRED(a33, 5);  WRED(a40, 6);  WRED(a42, 7);  WRED(a44, 8);  WRED(a51, 9);
    WRED(a53, 10); WRED(a55, 11); WRED(a60, 12); WRED(a62, 13); WRED(a64, 14);
    WRED(a66, 15); WRED(a71, 16); WRED(a73, 17); WRED(a75, 18); WRED(a77, 19);
    WRED(a80, 20); WRED(a82, 21); WRED(a84, 22); WRED(a86, 23); WRED(a88, 24);
    WRED(a91, 25); WRED(a93, 26); WRED(a95, 27); WRED(a97, 28); WRED(a99, 29);
    WRED(b11, 30); WRED(b22, 31); WRED(b31, 32); WRED(b33, 33); WRED(b42, 34);
    WRED(b44, 35); WRED(b51, 36); WRED(b53, 37); WRED(b55, 38); WRED(b62, 39);
    WRED(b64, 40); WRED(b66, 41); WRED(b71, 42); WRED(b73, 43); WRED(b75, 44);
    WRED(b77, 45); WRED(b82, 46); WRED(b84, 47); WRED(b86, 48); WRED(b88, 49);
    WRED(b91, 50); WRED(b93, 51); WRED(b95, 52); WRED(b97, 53); WRED(b99, 54);
    WRED(sgx, 55); WRED(sgx2, 56); WRED(sgy, 57); WRED(sgy2, 58); WRED(cnt, 59);
    __syncthreads();
    const int t = threadIdx.x;
    if (t < 60) {
        float s = red[t] + red[64 + t] + red[128 + t] + red[192 + t];
        pu[((long long)(b * 57 + blockIdx.x)) * 2048 + 1024 + t] = s;
    }
}

// ---------------------------------------------------------------------------
// Kernel D: sum 57 block-partials per batch, map moments -> Zernike coeffs,
// finalize stats.
// ---------------------------------------------------------------------------
__device__ int moment_index(int p, int a, int is_cos) {
    int ai = 0;
    for (int pp = 0; pp < 10; ++pp)
        for (int aa = (pp & 1); aa <= pp; aa += 2) {
            if (is_cos && pp == p && aa == a) return ai;
            ++ai;
        }
    for (int pp = 1; pp < 10; ++pp)
        for (int aa = ((pp & 1) ? 1 : 2); aa <= pp; aa += 2) {
            if (!is_cos && pp == p && aa == a) return ai;
            ++ai;
        }
    return 0;
}

__device__ float factf(int n) {
    float f = 1.0f;
    for (int i = 2; i <= n; ++i) f *= (float)i;
    return f;
}

__global__ void finalize_kernel(const float* __restrict__ pu,
                                const float* __restrict__ magmax,
                                float* __restrict__ out) {
    __shared__ float abf[64];
    const int b = blockIdx.x;
    const int j = threadIdx.x;
    if (j < 60) {
        float s = 0.0f;
        for (int i = 0; i < 57; ++i)
            s += pu[((long long)(b * 57 + i)) * 2048 + 1024 + j];
        abf[j] = s;
    }
    __syncthreads();
    if (j >= 60) return;
    const float NF = (float)NPIX;
    float val;
    if (j < 55) {
        int tt = j, n = 0;
        while (tt >= n + 1) { tt -= (n + 1); ++n; }
        int m = -n + 2 * tt;
        int am = m < 0 ? -m : m;
        float s = 0.0f;
        for (int k = 0; k <= (n - am) / 2; ++k) {
            float c = factf(n - k) /
                      (factf(k) * factf((n + am) / 2 - k) * factf((n - am) / 2 - k));
            if (k & 1) c = -c;
            int p = n - 2 * k;
            s += c * abf[moment_index(p, am, m >= 0 ? 1 : 0)];
        }
        val = s / abf[59];
    } else if (j == 55) {
        val = abf[55] / NF;
    } else if (j == 56) {
        val = abf[57] / NF;
    } else if (j == 57) {
        float sum = abf[55], sq = abf[56];
        val = sqrtf(fmaxf(0.0f, (sq - sum * sum / NF) / (NF - 1.0f)));
    } else if (j == 58) {
        float sum = abf[57], sq = abf[58];
        val = sqrtf(fmaxf(0.0f, (sq - sum * sum / NF) / (NF - 1.0f)));
    } else {
        val = magmax[b];
    }
    out[b * 60 + j] = val;
}

// ---------------------------------------------------------------------------
extern "C" void kernel_launch(void* const* d_in, const int* in_sizes, int n_in,
                              void* d_out, int out_size, void* d_ws, size_t ws_size,
                              hipStream_t stream) {
    (void)in_sizes; (void)n_in; (void)out_size; (void)ws_size;
    const float* x = (const float*)d_in[0];
    float* out = (float*)d_out;

    float* magmax = (float*)d_ws;                  // 32 floats (atomicMax target)
    float2* rf2 = (float2*)((char*)d_ws + 16384);  // [B][WR][H] float2 = 134.5 MB

    hipMemsetAsync(d_ws, 0, 16384, stream);
    row_fft_kernel<<<BATCH * 128, 256, 0, stream>>>(x, rf2);
    col_fft_kernel<<<(BATCH * WR) / 2, 128, 0, stream>>>(rf2, magmax);
    dim3 gridC(57, BATCH);
    stats_kernel<<<gridC, 256, 0, stream>>>((float*)rf2);
    finalize_kernel<<<BATCH, 64, 0, stream>>>((const float*)rf2, magmax, out);
}